// Round 7
// baseline (812.636 us; speedup 1.0000x reference)
//
#include <hip/hip_runtime.h>

// LocalEncoder on MI355X — round 14: B-operand direct-from-L2 (no LDS, no
// barriers for W). r13 post-mortem: fused phase 2 was latency-bound because
// every 16KB W slab paid a __syncthreads whose vmcnt(0) drain killed prefetch
// depth. But wout/wff1/wff2 are small L2-resident weights shared by all
// blocks; a B-fragment is 8 contiguous shorts -> load it per-wave straight
// from global. fused: phase 2 now barrier-free (compiler pipelines W loads);
// phase 1 + res_ln<704> keep LDS (dbuf) only for the block-local A tile
// (2 instead of 10 staged loads/wave/slab; LDS 80KB -> 16-48KB). qkv/attn
// unchanged as controls. A&S erf kept in fused epilogue.

#define DIM 256
#define DHEAD 32
#define NWIN 32
#define SEQ 4096
#define TOKENS 32768
#define FFP 704
#define ATT_SCALE_LOG2E 0.25501818642228136f

typedef __attribute__((ext_vector_type(4))) float f32x4;
typedef __attribute__((ext_vector_type(4))) short s16x4;
typedef __attribute__((ext_vector_type(8))) short s16x8;
typedef __attribute__((ext_vector_type(4))) _Float16 f16x4;
typedef __attribute__((ext_vector_type(8))) _Float16 f16x8;

__device__ __forceinline__ short f2bf(float f) {
  unsigned int u = __float_as_uint(f);
  u += 0x7fffu + ((u >> 16) & 1u);
  return (short)(u >> 16);
}

__device__ __forceinline__ float fast_exp2(float x) {
#if __has_builtin(__builtin_amdgcn_exp2f)
  return __builtin_amdgcn_exp2f(x);
#else
  return __expf(x * 0.6931471805599453f);
#endif
}

// A&S 7.1.26 erf-based exact GELU: |erf err| < 1.5e-7 (below bf16 rounding).
__device__ __forceinline__ float gelu_as(float g) {
  const float z = fabsf(g) * 0.70710678118654752440f;
#if __has_builtin(__builtin_amdgcn_rcpf)
  const float t = __builtin_amdgcn_rcpf(fmaf(0.3275911f, z, 1.0f));
#else
  const float t = 1.0f / fmaf(0.3275911f, z, 1.0f);
#endif
  const float e = fast_exp2(-z * z * 1.4426950408889634f);
  const float poly = t * fmaf(t, fmaf(t, fmaf(t, fmaf(t, 1.061405429f,
                     -1.453152027f), 1.421413741f), -0.284496736f), 0.254829592f);
  const float erfv = fmaf(-poly, e, 1.0f);
  const float se = (g < 0.0f) ? -erfv : erfv;
  return 0.5f * g * (1.0f + se);
}

__device__ __forceinline__ void gl_lds16(const short* g, short* l) {
  __builtin_amdgcn_global_load_lds(
      (const __attribute__((address_space(1))) void*)g,
      (__attribute__((address_space(3))) void*)l, 16, 0, 0);
}

// fragment read from a BK=64 swizzled tile: 16B block g (= kh*4+quad) of `row`
__device__ __forceinline__ s16x8 fragld(const short* lds, int row, int g) {
  return *(const s16x8*)(lds + row * 64 + ((g ^ (row & 7)) << 3));
}

// ---------------- copy + LayerNorm: x0 fp32 -> x fp32 copy + xn bf16 ----------------
__global__ void __launch_bounds__(256)
copy_ln(const float* __restrict__ x0, const float* __restrict__ gw,
        const float* __restrict__ bw, float* __restrict__ x, short* __restrict__ xn) {
  const int row = blockIdx.x * 4 + (threadIdx.x >> 6);
  const int lane = threadIdx.x & 63;
  const f32x4 v = *(const f32x4*)(x0 + (size_t)row * DIM + lane * 4);
  *(f32x4*)(x + (size_t)row * DIM + lane * 4) = v;
  float s = v[0] + v[1] + v[2] + v[3];
  float s2 = v[0]*v[0] + v[1]*v[1] + v[2]*v[2] + v[3]*v[3];
#pragma unroll
  for (int off = 32; off > 0; off >>= 1) {
    s  += __shfl_xor(s, off, 64);
    s2 += __shfl_xor(s2, off, 64);
  }
  const float mu = s * (1.0f / DIM);
  const float var = s2 * (1.0f / DIM) - mu * mu;
  const float rstd = rsqrtf(var + 1e-5f);
  const f32x4 gv = *(const f32x4*)(gw + lane * 4);
  const f32x4 bv = *(const f32x4*)(bw + lane * 4);
  s16x4 o;
#pragma unroll
  for (int j = 0; j < 4; ++j) o[j] = f2bf((v[j] - mu) * rstd * gv[j] + bv[j]);
  *(s16x4*)(xn + (size_t)row * DIM + lane * 4) = o;
}

// -------- Residual GEMM + fused next-LN (FF2 path): x += A.W^T; xn = LN(x) --------
// 256 threads, 4 waves; block tile 64 x 256, wave tile 64x64. BK=64.
// A tile staged in LDS (dbuf, 2 loads/wave/slab); W fragments DIRECT from
// global (L2-resident, no LDS/barrier cost). One barrier per slab.
template<int K, bool DO_LN>
__global__ void __launch_bounds__(256)
gemm_res_ln(const short* __restrict__ A, const short* __restrict__ W,
            float* __restrict__ x, const float* __restrict__ lng,
            const float* __restrict__ lnb, short* __restrict__ xn) {
  __shared__ short As[2][64 * 64];
  const int tid = threadIdx.x;
  const int lane = tid & 63;
  const int w = tid >> 6;              // 0..3
  const int ln16 = lane & 15;
  const int quad = lane >> 4;
  const int m_blk = blockIdx.x * 64;
  const int n0w = w * 64;
  const int srow = lane >> 3;
  const int swz = (lane & 7) ^ srow;

  // A staging: 8 row-groups, wave w does grp = w, w+4
  const short* sg[2];
  short* dg0[2];
  short* dg1[2];
#pragma unroll
  for (int i = 0; i < 2; ++i) {
    const int grp = w + i * 4;
    sg[i] = A + (size_t)(m_blk + grp * 8 + srow) * K + swz * 8;
    dg0[i] = &As[0][grp * 512];
    dg1[i] = &As[1][grp * 512];
  }

  // W row pointers for this wave's 64 output cols
  const short* wr[4];
#pragma unroll
  for (int nt = 0; nt < 4; ++nt)
    wr[nt] = W + (size_t)(n0w + nt * 16 + ln16) * K + quad * 8;

  constexpr int NS = K / 64;
  f32x4 acc[4][4] = {};

#pragma unroll
  for (int i = 0; i < 2; ++i) gl_lds16(sg[i], dg0[i]);
  __syncthreads();

#pragma unroll
  for (int s = 0; s < NS; ++s) {
    if (s + 1 < NS) {
#pragma unroll
      for (int i = 0; i < 2; ++i)
        gl_lds16(sg[i] + (s + 1) * 64, ((s & 1) ? dg0 : dg1)[i]);
    }
    const short* Ac = (s & 1) ? As[1] : As[0];
    s16x8 af[2][4], bf[2][4];
#pragma unroll
    for (int nt = 0; nt < 4; ++nt) {
      bf[0][nt] = *(const s16x8*)(wr[nt] + s * 64);
      bf[1][nt] = *(const s16x8*)(wr[nt] + s * 64 + 32);
    }
#pragma unroll
    for (int kh = 0; kh < 2; ++kh)
#pragma unroll
      for (int mt = 0; mt < 4; ++mt)
        af[kh][mt] = fragld(Ac, mt * 16 + ln16, kh * 4 + quad);
#pragma unroll
    for (int kh = 0; kh < 2; ++kh)
#pragma unroll
      for (int mt = 0; mt < 4; ++mt)
#pragma unroll
        for (int nt = 0; nt < 4; ++nt)
          acc[mt][nt] = __builtin_amdgcn_mfma_f32_16x16x32_bf16(af[kh][mt], bf[kh][nt], acc[mt][nt], 0, 0, 0);
    __syncthreads();
  }

  // residual add; keep new x values in acc
#pragma unroll
  for (int mt = 0; mt < 4; ++mt)
#pragma unroll
    for (int nt = 0; nt < 4; ++nt)
#pragma unroll
      for (int r = 0; r < 4; ++r) {
        const size_t idx = (size_t)(m_blk + mt * 16 + quad * 4 + r) * DIM
                           + n0w + nt * 16 + ln16;
        const float v = x[idx] + acc[mt][nt][r];
        acc[mt][nt][r] = v;
        x[idx] = v;
      }

  if (DO_LN) {
    float2* red = (float2*)As[0];   // all As reads completed at final loop barrier
#pragma unroll
    for (int mt = 0; mt < 4; ++mt)
#pragma unroll
      for (int r = 0; r < 4; ++r) {
        float s = 0.f, s2 = 0.f;
#pragma unroll
        for (int nt = 0; nt < 4; ++nt) {
          const float v = acc[mt][nt][r];
          s += v; s2 += v * v;
        }
#pragma unroll
        for (int off = 1; off < 16; off <<= 1) {
          s  += __shfl_xor(s, off, 64);
          s2 += __shfl_xor(s2, off, 64);
        }
        if (ln16 == 0)
          red[(mt * 16 + quad * 4 + r) * 4 + w] = float2{s, s2};
      }
    __syncthreads();

    float gv[4], bv[4];
#pragma unroll
    for (int nt = 0; nt < 4; ++nt) {
      gv[nt] = lng[n0w + nt * 16 + ln16];
      bv[nt] = lnb[n0w + nt * 16 + ln16];
    }
#pragma unroll
    for (int mt = 0; mt < 4; ++mt)
#pragma unroll
      for (int r = 0; r < 4; ++r) {
        const int row = mt * 16 + quad * 4 + r;
        const float2 t0 = red[row * 4 + 0];
        const float2 t1 = red[row * 4 + 1];
        const float2 t2 = red[row * 4 + 2];
        const float2 t3 = red[row * 4 + 3];
        const float s  = (t0.x + t1.x) + (t2.x + t3.x);
        const float s2 = (t0.y + t1.y) + (t2.y + t3.y);
        const float mu = s * (1.0f / DIM);
        const float var = s2 * (1.0f / DIM) - mu * mu;
        const float rstd = rsqrtf(var + 1e-5f);
#pragma unroll
        for (int nt = 0; nt < 4; ++nt)
          xn[(size_t)(m_blk + row) * DIM + n0w + nt * 16 + ln16] =
              f2bf((acc[mt][nt][r] - mu) * rstd * gv[nt] + bv[nt]);
      }
  }
}

// ---- FUSED: attn-out projection + residual + LN + FF1 GEGLU -> y ----
// Phase 1: out-proj GEMM, A staged in LDS (dbuf), W=wout direct from global.
// LN result -> LDS xn tile (swizzled). Phase 2: BARRIER-FREE — W_ff1 fragments
// direct from global (L2-resident), A-frags from local xn tile; y = a*gelu(g).
__global__ void __launch_bounds__(256)
fused_out_ff1(const short* __restrict__ A, const short* __restrict__ W,
              float* __restrict__ x, const float* __restrict__ lng,
              const float* __restrict__ lnb, const short* __restrict__ wff,
              short* __restrict__ y) {
  __shared__ short As[2][64 * 64];
  __shared__ short xnl[64 * 256];
  const int tid = threadIdx.x;
  const int lane = tid & 63;
  const int w = tid >> 6;              // 0..3
  const int ln16 = lane & 15;
  const int quad = lane >> 4;
  const int m_blk = blockIdx.x * 64;
  const int n0w = w * 64;
  const int srow = lane >> 3;
  const int swz = (lane & 7) ^ srow;

  // ---------- phase 1: out-proj GEMM (K=256) ----------
  const short* sg[2];
  short* dg0[2];
  short* dg1[2];
#pragma unroll
  for (int i = 0; i < 2; ++i) {
    const int grp = w + i * 4;
    sg[i] = A + (size_t)(m_blk + grp * 8 + srow) * DIM + swz * 8;
    dg0[i] = &As[0][grp * 512];
    dg1[i] = &As[1][grp * 512];
  }
  const short* wr[4];
#pragma unroll
  for (int nt = 0; nt < 4; ++nt)
    wr[nt] = W + (size_t)(n0w + nt * 16 + ln16) * DIM + quad * 8;

  f32x4 acc[4][4] = {};
#pragma unroll
  for (int i = 0; i < 2; ++i) gl_lds16(sg[i], dg0[i]);
  __syncthreads();

#pragma unroll
  for (int s = 0; s < 4; ++s) {
    if (s + 1 < 4) {
#pragma unroll
      for (int i = 0; i < 2; ++i)
        gl_lds16(sg[i] + (s + 1) * 64, ((s & 1) ? dg0 : dg1)[i]);
    }
    const short* Ac = (s & 1) ? As[1] : As[0];
    s16x8 af[2][4], bf[2][4];
#pragma unroll
    for (int nt = 0; nt < 4; ++nt) {
      bf[0][nt] = *(const s16x8*)(wr[nt] + s * 64);
      bf[1][nt] = *(const s16x8*)(wr[nt] + s * 64 + 32);
    }
#pragma unroll
    for (int kh = 0; kh < 2; ++kh)
#pragma unroll
      for (int mt = 0; mt < 4; ++mt)
        af[kh][mt] = fragld(Ac, mt * 16 + ln16, kh * 4 + quad);
#pragma unroll
    for (int kh = 0; kh < 2; ++kh)
#pragma unroll
      for (int mt = 0; mt < 4; ++mt)
#pragma unroll
        for (int nt = 0; nt < 4; ++nt)
          acc[mt][nt] = __builtin_amdgcn_mfma_f32_16x16x32_bf16(af[kh][mt], bf[kh][nt], acc[mt][nt], 0, 0, 0);
    __syncthreads();
  }

  // residual add; keep new x values in acc
#pragma unroll
  for (int mt = 0; mt < 4; ++mt)
#pragma unroll
    for (int nt = 0; nt < 4; ++nt)
#pragma unroll
      for (int r = 0; r < 4; ++r) {
        const size_t idx = (size_t)(m_blk + mt * 16 + quad * 4 + r) * DIM
                           + n0w + nt * 16 + ln16;
        const float v = x[idx] + acc[mt][nt][r];
        acc[mt][nt][r] = v;
        x[idx] = v;
      }

  // LN reduce (red in As[0]; As reads all done at final phase-1 barrier)
  {
    float2* red = (float2*)As[0];
#pragma unroll
    for (int mt = 0; mt < 4; ++mt)
#pragma unroll
      for (int r = 0; r < 4; ++r) {
        float s = 0.f, s2 = 0.f;
#pragma unroll
        for (int nt = 0; nt < 4; ++nt) {
          const float v = acc[mt][nt][r];
          s += v; s2 += v * v;
        }
#pragma unroll
        for (int off = 1; off < 16; off <<= 1) {
          s  += __shfl_xor(s, off, 64);
          s2 += __shfl_xor(s2, off, 64);
        }
        if (ln16 == 0)
          red[(mt * 16 + quad * 4 + r) * 4 + w] = float2{s, s2};
      }
    __syncthreads();

    float gv[4], bv[4];
#pragma unroll
    for (int nt = 0; nt < 4; ++nt) {
      gv[nt] = lng[n0w + nt * 16 + ln16];
      bv[nt] = lnb[n0w + nt * 16 + ln16];
    }
    // LN result -> LDS xn tile, stored so fragld(xnl + s*4096, row, g) works:
    // sub-tile s=col>>6, pos ((col&63)>>3 ^ (row&7))*8 + (col&7)
#pragma unroll
    for (int mt = 0; mt < 4; ++mt)
#pragma unroll
      for (int r = 0; r < 4; ++r) {
        const int row = mt * 16 + quad * 4 + r;
        const float2 t0 = red[row * 4 + 0];
        const float2 t1 = red[row * 4 + 1];
        const float2 t2 = red[row * 4 + 2];
        const float2 t3 = red[row * 4 + 3];
        const float s  = (t0.x + t1.x) + (t2.x + t3.x);
        const float s2 = (t0.y + t1.y) + (t2.y + t3.y);
        const float mu = s * (1.0f / DIM);
        const float var = s2 * (1.0f / DIM) - mu * mu;
        const float rstd = rsqrtf(var + 1e-5f);
#pragma unroll
        for (int nt = 0; nt < 4; ++nt) {
          const int colin = nt * 16 + ln16;          // 0..63 within sub-tile w
          const int pos = ((colin >> 3) ^ (row & 7)) * 8 + (colin & 7);
          xnl[w * 4096 + row * 64 + pos] =
              f2bf((acc[mt][nt][r] - mu) * rstd * gv[nt] + bv[nt]);
        }
      }
  }
  __syncthreads();   // xn tile ready; NO barriers after this point

  // ---------- phase 2: FF1 GEGLU, 11 chunks, barrier-free ----------
  const short* wfa = wff + (size_t)(w * 16 + ln16) * DIM + quad * 8;         // a-half
  const short* wfg = wff + (size_t)(FFP + w * 16 + ln16) * DIM + quad * 8;   // g-half
  for (int c = 0; c < 11; ++c) {
    f32x4 aA[4] = {}, aG[4] = {};
    const size_t crow = (size_t)c * 64 * DIM;
#pragma unroll
    for (int s = 0; s < 4; ++s) {
      s16x8 wa[2], wg[2];
      wa[0] = *(const s16x8*)(wfa + crow + s * 64);
      wa[1] = *(const s16x8*)(wfa + crow + s * 64 + 32);
      wg[0] = *(const s16x8*)(wfg + crow + s * 64);
      wg[1] = *(const s16x8*)(wfg + crow + s * 64 + 32);
      const short* Xs = xnl + s * 4096;
      s16x8 af[2][4];
#pragma unroll
      for (int kh = 0; kh < 2; ++kh)
#pragma unroll
        for (int mt = 0; mt < 4; ++mt)
          af[kh][mt] = fragld(Xs, mt * 16 + ln16, kh * 4 + quad);
#pragma unroll
      for (int kh = 0; kh < 2; ++kh)
#pragma unroll
        for (int mt = 0; mt < 4; ++mt) {
          aA[mt] = __builtin_amdgcn_mfma_f32_16x16x32_bf16(af[kh][mt], wa[kh], aA[mt], 0, 0, 0);
          aG[mt] = __builtin_amdgcn_mfma_f32_16x16x32_bf16(af[kh][mt], wg[kh], aG[mt], 0, 0, 0);
        }
    }
    const int col = c * 64 + w * 16 + ln16;
#pragma unroll
    for (int mt = 0; mt < 4; ++mt)
#pragma unroll
      for (int r = 0; r < 4; ++r)
        y[(size_t)(m_blk + mt * 16 + quad * 4 + r) * FFP + col] =
            f2bf(aA[mt][r] * gelu_as(aG[mt][r]));
  }
}

// -------- QKV GEMM (BK=64 swizzled, 2 m-tiles/block): Q,K head-major; V permuted f16 --------
__global__ void __launch_bounds__(256)
gemm_qkv(const short* __restrict__ A, const short* __restrict__ W,
         short* __restrict__ qh, short* __restrict__ kh_, _Float16* __restrict__ vp) {
  __shared__ short As[128 * 64];
  __shared__ short Bs[128 * 64];
  const int tid = threadIdx.x;
  const int lane = tid & 63;
  const int w = tid >> 6;
  const int ln16 = lane & 15;
  const int quad = lane >> 4;
  const int m_blk0 = blockIdx.x * 256;     // two 128-row tiles
  const int n_blk = blockIdx.y * 128;
  const int m0w = (w & 1) * 64;
  const int n0w = (w >> 1) * 64;
  const int srow = lane >> 3;
  const int swz = (lane & 7) ^ srow;

  int aoff[4];
  const short* bsrc[4];
  short* dst[8];
#pragma unroll
  for (int i = 0; i < 8; ++i) {
    const int grp = w + i * 4;
    if (i < 4) {
      aoff[i] = (grp * 8 + srow) * DIM + swz * 8;
      dst[i] = As + grp * 512;
    } else {
      const int gb = grp - 16;
      bsrc[i - 4] = W + (size_t)(n_blk + gb * 8 + srow) * DIM + swz * 8;
      dst[i] = Bs + gb * 512;
    }
  }

  auto stage = [&](int t2, int s2) {
    const short* At = A + (size_t)(m_blk0 + t2 * 128) * DIM + s2 * 64;
#pragma unroll
    for (int i = 0; i < 4; ++i) gl_lds16(At + aoff[i], dst[i]);
#pragma unroll
    for (int i = 0; i < 4; ++i) gl_lds16(bsrc[i] + s2 * 64, dst[i + 4]);
  };

  stage(0, 0);

#pragma unroll
  for (int t = 0; t < 2; ++t) {
    f32x4 acc[4][4] = {};
#pragma unroll
    for (int s = 0; s < 4; ++s) {
      __syncthreads();
      s16x8 af[2][4], bf[2][4];
#pragma unroll
      for (int kh = 0; kh < 2; ++kh) {
#pragma unroll
        for (int mt = 0; mt < 4; ++mt)
          af[kh][mt] = fragld(As, m0w + mt * 16 + ln16, kh * 4 + quad);
#pragma unroll
        for (int nt = 0; nt < 4; ++nt)
          bf[kh][nt] = fragld(Bs, n0w + nt * 16 + ln16, kh * 4 + quad);
      }
#pragma unroll
      for (int kh = 0; kh < 2; ++kh)
#pragma unroll
        for (int mt = 0; mt < 4; ++mt)
#pragma unroll
          for (int nt = 0; nt < 4; ++nt)
            acc[mt][nt] = __builtin_amdgcn_mfma_f32_16x16x32_bf16(af[kh][mt], bf[kh][nt], acc[mt][nt], 0, 0, 0);
      if (!(t == 1 && s == 3)) {
        __syncthreads();
        if (s == 3) stage(t + 1, 0);
        else        stage(t, s + 1);
      }
    }

#pragma unroll
    for (int mt = 0; mt < 4; ++mt) {
      const int m = m_blk0 + t * 128 + m0w + mt * 16 + quad * 4;
      const int bb = m >> 12;
      const int n = m & 4095;
#pragma unroll
      for (int nt = 0; nt < 4; ++nt) {
        const int f = n_blk + n0w + nt * 16;
        if (f < 512) {
          const int ff = f & 255;
          short* dstp = (f < 256 ? qh : kh_)
                       + ((size_t)(bb * 8 + (ff >> 5)) * SEQ + n) * 32 + (ff & 16) + ln16;
#pragma unroll
          for (int r = 0; r < 4; ++r) dstp[r * 32] = f2bf(acc[mt][nt][r]);
        } else {
          const int ff = f - 512;
          const int h = ff >> 5;
          const int d = (ff & 16) + ln16;
          const int within = n & 31;
          const int pos = (n & ~31) + ((within & 12) << 1) + ((within >> 4) << 2);
          f16x4 o;
#pragma unroll
          for (int r = 0; r < 4; ++r) o[r] = (_Float16)acc[mt][nt][r];
          *(f16x4*)(vp + ((size_t)(bb * 8 + h) * 32 + d) * SEQ + pos) = o;
        }
      }
    }
  }
}

// ---------------- Local attention: wave = half-window (4 q-tiles), prefetched ----------------
__global__ void __launch_bounds__(256)
attn_kernel(const short* __restrict__ qh, const short* __restrict__ kh,
            const _Float16* __restrict__ vp, short* __restrict__ out) {
  const int blk = blockIdx.x;              // 1024 blocks
  const int lane = threadIdx.x & 63;
  const int wid = threadIdx.x >> 6;
  const int ln16 = lane & 15;
  const int quad = lane >> 4;

  const int w = (blk & 15) * 2 + (wid >> 1);
  const int h = (blk >> 4) & 7;
  const int b = blk >> 7;
  const int plane = b * 8 + h;
  const int tok0 = w * 128 + (wid & 1) * 64;
  const int ktok = w * 128 - 128;
  const int c0 = (w == 0) ? 4 : 0;
  const int c1 = (w == NWIN - 1) ? 8 : 12;

  const short* qp = qh + ((size_t)plane * SEQ + tok0) * 32;
  s16x8 qf[4];
#pragma unroll
  for (int qi = 0; qi < 4; ++qi)
    qf[qi] = *(const s16x8*)(qp + (qi * 16 + ln16) * 32 + quad * 8);

  const short* kp = kh + ((size_t)plane * SEQ + ktok) * 32;
  const _Float16* vb = vp + ((size_t)plane * 32 + ln16) * SEQ + ktok;

  float lsum[4] = {0.f, 0.f, 0.f, 0.f};
  f32x4 ot[4][2] = {};

  s16x8 kc0 = *(const s16x8*)(kp + (c0 * 32 + ln16) * 32 + quad * 8);
  s16x8 kc1 = *(const s16x8*)(kp + (c0 * 32 + 16 + ln16) * 32 + quad * 8);
  f16x8 vc0 = *(const f16x8*)(vb + c0 * 32 + quad * 8);
  f16x8 vc1 = *(const f16x8*)(vb + (size_t)16 * SEQ + c0 * 32 + quad * 8);

  for (int c = c0; c < c1; ++c) {
    const int cn = (c + 1 < c1) ? c + 1 : c;
    s16x8 kn0 = *(const s16x8*)(kp + (cn * 32 + ln16) * 32 + quad * 8);
    s16x8 kn1 = *(const s16x8*)(kp + (cn * 32 + 16 + ln16) * 32 + quad * 8);
    f16x8 vn0 = *(const f16x8*)(vb + cn * 32 + quad * 8);
    f16x8 vn1 = *(const f16x8*)(vb + (size_t)16 * SEQ + cn * 32 + quad * 8);

    const f16x4 v00 = __builtin_shufflevector(vc0, vc0, 0, 1, 2, 3);
    const f16x4 v10 = __builtin_shufflevector(vc0, vc0, 4, 5, 6, 7);
    const f16x4 v01 = __builtin_shufflevector(vc1, vc1, 0, 1, 2, 3);
    const f16x4 v11 = __builtin_shufflevector(vc1, vc1, 4, 5, 6, 7);

#pragma unroll
    for (int qi = 0; qi < 4; ++qi) {
      const f32x4 z = {0.f, 0.f, 0.f, 0.f};
      f32x4 st0 = __builtin_amdgcn_mfma_f32_16x16x32_bf16(kc0, qf[qi], z, 0, 0, 0);
      f32x4 st1 = __builtin_amdgcn_mfma_f32_16x16x32_bf16(kc1, qf[qi], z, 0, 0, 0);
      float p[8];
#pragma unroll
      for (int r = 0; r < 4; ++r) {
        p[r]     = fast_exp2(st0[r] * ATT_SCALE_LOG2E);
        p[4 + r] = fast_exp2(st1[r] * ATT_SCALE_LOG2E);
      }
      lsum[qi] += ((p[0] + p[1]) + (p[2] + p[3])) + ((p[4] + p[5]) + (p[6] + p[7]));
      f16x4 pa, pb;
#pragma unroll
      for (int r = 0; r < 4; ++r) { pa[r] = (_Float16)p[r]; pb[r] = (_Float16)p[4 + r]; }
      ot[qi][0] = __builtin_amdgcn_mfma_f32_16x16x16f16(pa, v00, ot[qi][0], 0, 0, 0);
      ot[qi][1] = __builtin_amdgcn_mfma_f32_16x16x16f16(pa, v01, ot[qi][1], 0, 0, 0);
      ot[qi][0] = __builtin_amdgcn_mfma_f32_16x16x16f16(pb, v10, ot[qi][0], 0, 0, 0);
      ot[qi][1] = __builtin_amdgcn_mfma_f32_16x16x16f16(pb, v11, ot[qi][1], 0, 0, 0);
    }
    kc0 = kn0; kc1 = kn1; vc0 = vn0; vc1 = vn1;
  }

#pragma unroll
  for (int qi = 0; qi < 4; ++qi) {
    float l = lsum[qi];
    l += __shfl_xor(l, 16, 64);
    l += __shfl_xor(l, 32, 64);
    const float inv = 1.0f / l;
#pragma unroll
    for (int dt = 0; dt < 2; ++dt)
#pragma unroll
      for (int r = 0; r < 4; ++r)
        out[(size_t)(b * SEQ + tok0 + qi * 16 + quad * 4 + r) * DIM
            + h * DHEAD + dt * 16 + ln16] = f2bf(ot[qi][dt][r] * inv);
  }
}

// ---------------- merged weight conversion fp32 -> bf16 (with FF padding) ----------------
__global__ void cvt_all(const float* __restrict__ qkv_w, const float* __restrict__ out_w,
                        const float* __restrict__ ff_w1, const float* __restrict__ ff_w2,
                        short* __restrict__ wqkv, short* __restrict__ wout,
                        short* __restrict__ wff1, short* __restrict__ wff2) {
  int i = blockIdx.x * 256 + threadIdx.x;
  if (i < 786432) { wqkv[i] = f2bf(qkv_w[i]); return; }
  i -= 786432;
  if (i < 262144) { wout[i] = f2bf(out_w[i]); return; }
  i -= 262144;
  if (i < 1441792) {
    const int c = i & 255;
    const int rl = i >> 8;
    const int l = rl / 1408;
    const int r = rl - l * 1408;
    const int half = r / FFP;
    const int rr = r - half * FFP;
    const float v = (rr < 682) ? ff_w1[((size_t)(l * 1364 + half * 682 + rr)) * 256 + c] : 0.0f;
    wff1[i] = f2bf(v);
    return;
  }
  i -= 1441792;
  if (i < 720896) {
    const int c = i % FFP;
    const int t = i / FFP;
    const float v = (c < 682) ? ff_w2[(size_t)t * 682 + c] : 0.0f;
    wff2[i] = f2bf(v);
  }
}

// ---------------- driver ----------------
extern "C" void kernel_launch(void* const* d_in, const int* in_sizes, int n_in,
                              void* d_out, int out_size, void* d_ws, size_t ws_size,
                              hipStream_t stream) {
  const float* x0    = (const float*)d_in[0];
  const float* ln1_g = (const float*)d_in[2];
  const float* ln1_b = (const float*)d_in[3];
  const float* qkv_w = (const float*)d_in[4];
  const float* out_w = (const float*)d_in[5];
  const float* ln2_g = (const float*)d_in[6];
  const float* ln2_b = (const float*)d_in[7];
  const float* ff_w1 = (const float*)d_in[8];
  const float* ff_w2 = (const float*)d_in[9];
  float* x = (float*)d_out;

  char* ws = (char*)d_ws;
  short* wqkv = (short*)(ws);                    //  4*768*256 bf16
  short* wout = (short*)(ws + 1572864);          //  4*256*256
  short* wff1 = (short*)(ws + 2097152);          //  4*1408*256
  short* wff2 = (short*)(ws + 4980736);          //  4*256*704
  short* xn   = (short*)(ws + 6422528);          //  32768*256 (LN out / attn out)
  short*    qhb = (short*)(ws + 23199744);                 // 16.8MB qkv->attn
  short*    khb = (short*)(ws + 23199744 + 16777216);      // 16.8MB qkv->attn
  _Float16* vpb = (_Float16*)(ws + 23199744 + 33554432);   // 16.8MB qkv->attn
  short*    yb  = (short*)(ws + 23199744);                 // 46.1MB fused->ff2 (disjoint lifetime)

  copy_ln<<<8192, 256, 0, stream>>>(x0, ln1_g, ln1_b, x, xn);
  cvt_all<<<12544, 256, 0, stream>>>(qkv_w, out_w, ff_w1, ff_w2, wqkv, wout, wff1, wff2);

  for (int l = 0; l < 4; ++l) {
    gemm_qkv<<<dim3(128, 6), 256, 0, stream>>>(
        xn, wqkv + (size_t)l * 768 * DIM, qhb, khb, vpb);
    attn_kernel<<<1024, 256, 0, stream>>>(qhb, khb, vpb, xn);
    fused_out_ff1<<<512, 256, 0, stream>>>(
        xn, wout + (size_t)l * DIM * DIM, x,
        ln2_g + l * DIM, ln2_b + l * DIM,
        wff1 + (size_t)l * 2 * FFP * DIM, yb);
    if (l < 3)
      gemm_res_ln<FFP, true><<<512, 256, 0, stream>>>(
          yb, wff2 + (size_t)l * DIM * FFP, x,
          ln1_g + (l + 1) * DIM, ln1_b + (l + 1) * DIM, xn);
    else
      gemm_res_ln<FFP, false><<<512, 256, 0, stream>>>(
          yb, wff2 + (size_t)l * DIM * FFP, x, nullptr, nullptr, nullptr);
  }
}

// Round 8
// 709.299 us; speedup vs baseline: 1.1457x; 1.1457x over previous
//
#include <hip/hip_runtime.h>

// LocalEncoder on MI355X — round 15: r13 base + counted-vmcnt raw barriers.
// r14 post-mortem: direct-from-global B fragments REGRESSED (68.5->75.3us,
// VGPR 100->124) — L2 latency landed in the MFMA operand chain with no TLP.
// Reverted to r13 (best, 718.6us). This round attacks r13's real stall: each
// phase-2 W slab pays __syncthreads' implicit vmcnt(0) full prefetch drain.
// Guide T3/T4: raw s_barrier + counted s_waitcnt vmcnt(N) lets slab s+2's
// global_load_lds stay in flight across barriers. Applied to fused phase 2
// (vmcnt(4), last slab 0) and res_ln<704> (vmcnt(10)); both keep 2 barriers/
// slab with lgkmcnt(0) before the overwrite barrier. LN-reduce barriers are
// lgkmcnt-only so stage2(0/1) prefetch survives. Phase 1 / qkv / attn as r13.

#define DIM 256
#define DHEAD 32
#define NWIN 32
#define SEQ 4096
#define TOKENS 32768
#define FFP 704
#define ATT_SCALE_LOG2E 0.25501818642228136f

typedef __attribute__((ext_vector_type(4))) float f32x4;
typedef __attribute__((ext_vector_type(4))) short s16x4;
typedef __attribute__((ext_vector_type(8))) short s16x8;
typedef __attribute__((ext_vector_type(4))) _Float16 f16x4;
typedef __attribute__((ext_vector_type(8))) _Float16 f16x8;

__device__ __forceinline__ short f2bf(float f) {
  unsigned int u = __float_as_uint(f);
  u += 0x7fffu + ((u >> 16) & 1u);
  return (short)(u >> 16);
}

__device__ __forceinline__ float fast_exp2(float x) {
#if __has_builtin(__builtin_amdgcn_exp2f)
  return __builtin_amdgcn_exp2f(x);
#else
  return __expf(x * 0.6931471805599453f);
#endif
}

// A&S 7.1.26 erf-based exact GELU: |erf err| < 1.5e-7 (below bf16 rounding).
__device__ __forceinline__ float gelu_as(float g) {
  const float z = fabsf(g) * 0.70710678118654752440f;
#if __has_builtin(__builtin_amdgcn_rcpf)
  const float t = __builtin_amdgcn_rcpf(fmaf(0.3275911f, z, 1.0f));
#else
  const float t = 1.0f / fmaf(0.3275911f, z, 1.0f);
#endif
  const float e = fast_exp2(-z * z * 1.4426950408889634f);
  const float poly = t * fmaf(t, fmaf(t, fmaf(t, fmaf(t, 1.061405429f,
                     -1.453152027f), 1.421413741f), -0.284496736f), 0.254829592f);
  const float erfv = fmaf(-poly, e, 1.0f);
  const float se = (g < 0.0f) ? -erfv : erfv;
  return 0.5f * g * (1.0f + se);
}

__device__ __forceinline__ void gl_lds16(const short* g, short* l) {
  __builtin_amdgcn_global_load_lds(
      (const __attribute__((address_space(1))) void*)g,
      (__attribute__((address_space(3))) void*)l, 16, 0, 0);
}

// fragment read from a BK=64 swizzled tile: 16B block g (= kh*4+quad) of `row`
__device__ __forceinline__ s16x8 fragld(const short* lds, int row, int g) {
  return *(const s16x8*)(lds + row * 64 + ((g ^ (row & 7)) << 3));
}

// ---------------- copy + LayerNorm: x0 fp32 -> x fp32 copy + xn bf16 ----------------
__global__ void __launch_bounds__(256)
copy_ln(const float* __restrict__ x0, const float* __restrict__ gw,
        const float* __restrict__ bw, float* __restrict__ x, short* __restrict__ xn) {
  const int row = blockIdx.x * 4 + (threadIdx.x >> 6);
  const int lane = threadIdx.x & 63;
  const f32x4 v = *(const f32x4*)(x0 + (size_t)row * DIM + lane * 4);
  *(f32x4*)(x + (size_t)row * DIM + lane * 4) = v;
  float s = v[0] + v[1] + v[2] + v[3];
  float s2 = v[0]*v[0] + v[1]*v[1] + v[2]*v[2] + v[3]*v[3];
#pragma unroll
  for (int off = 32; off > 0; off >>= 1) {
    s  += __shfl_xor(s, off, 64);
    s2 += __shfl_xor(s2, off, 64);
  }
  const float mu = s * (1.0f / DIM);
  const float var = s2 * (1.0f / DIM) - mu * mu;
  const float rstd = rsqrtf(var + 1e-5f);
  const f32x4 gv = *(const f32x4*)(gw + lane * 4);
  const f32x4 bv = *(const f32x4*)(bw + lane * 4);
  s16x4 o;
#pragma unroll
  for (int j = 0; j < 4; ++j) o[j] = f2bf((v[j] - mu) * rstd * gv[j] + bv[j]);
  *(s16x4*)(xn + (size_t)row * DIM + lane * 4) = o;
}

// -------- Residual GEMM + fused next-LN (FF2 path): x += A.W^T; xn = LN(x) --------
// 256 threads, 4 waves; block tile 64 x 256, wave tile 64x64. BK=64, swizzled,
// dbuf LDS (80KB -> 2 blocks/CU). Counted-vmcnt raw barriers: stage s+2 stays
// in flight across barriers (vmcnt(10) = the 10 loads of slab s+1).
template<int K, bool DO_LN>
__global__ void __launch_bounds__(256, 2)
gemm_res_ln(const short* __restrict__ A, const short* __restrict__ W,
            float* __restrict__ x, const float* __restrict__ lng,
            const float* __restrict__ lnb, short* __restrict__ xn) {
  __shared__ short As[2][64 * 64];
  __shared__ short Bs[2][256 * 64];
  const int tid = threadIdx.x;
  const int lane = tid & 63;
  const int w = tid >> 6;              // 0..3
  const int ln16 = lane & 15;
  const int quad = lane >> 4;
  const int m_blk = blockIdx.x * 64;
  const int n0w = w * 64;
  const int srow = lane >> 3;
  const int swz = (lane & 7) ^ srow;

  // 40 staging groups of 8 rows: 0..7 = A, 8..39 = B. Wave w: grp = w + i*4.
  const short* sg[10];
  short* dg0[10];
  short* dg1[10];
#pragma unroll
  for (int i = 0; i < 10; ++i) {
    const int grp = w + i * 4;
    if (grp < 8) {
      sg[i] = A + (size_t)(m_blk + grp * 8 + srow) * K + swz * 8;
      dg0[i] = &As[0][grp * 512];
      dg1[i] = &As[1][grp * 512];
    } else {
      const int gb = grp - 8;
      sg[i] = W + (size_t)(gb * 8 + srow) * K + swz * 8;
      dg0[i] = &Bs[0][gb * 512];
      dg1[i] = &Bs[1][gb * 512];
    }
  }

  constexpr int NS = K / 64;
  f32x4 acc[4][4] = {};

  // prologue: stage slabs 0 and 1 (buffers 0, 1)
#pragma unroll
  for (int i = 0; i < 10; ++i) gl_lds16(sg[i], dg0[i]);
#pragma unroll
  for (int i = 0; i < 10; ++i) gl_lds16(sg[i] + 64, dg1[i]);

#pragma unroll
  for (int s = 0; s < NS; ++s) {
    // slab s complete when only slab s+1's 10 loads may remain in flight
    if (s + 1 < NS) asm volatile("s_waitcnt vmcnt(10)" ::: "memory");
    else            asm volatile("s_waitcnt vmcnt(0)" ::: "memory");
    __builtin_amdgcn_s_barrier();
    const short* Ac = (s & 1) ? As[1] : As[0];
    const short* Bc = (s & 1) ? Bs[1] : Bs[0];
    s16x8 af[2][4], bf[2][4];
#pragma unroll
    for (int kh = 0; kh < 2; ++kh) {
#pragma unroll
      for (int mt = 0; mt < 4; ++mt)
        af[kh][mt] = fragld(Ac, mt * 16 + ln16, kh * 4 + quad);
#pragma unroll
      for (int nt = 0; nt < 4; ++nt)
        bf[kh][nt] = fragld(Bc, n0w + nt * 16 + ln16, kh * 4 + quad);
    }
#pragma unroll
    for (int kh = 0; kh < 2; ++kh)
#pragma unroll
      for (int mt = 0; mt < 4; ++mt)
#pragma unroll
        for (int nt = 0; nt < 4; ++nt)
          acc[mt][nt] = __builtin_amdgcn_mfma_f32_16x16x32_bf16(af[kh][mt], bf[kh][nt], acc[mt][nt], 0, 0, 0);
    // all this wave's LDS reads are complete; barrier -> safe to overwrite buf
    asm volatile("s_waitcnt lgkmcnt(0)" ::: "memory");
    __builtin_amdgcn_s_barrier();
    if (s + 2 < NS) {
#pragma unroll
      for (int i = 0; i < 10; ++i)
        gl_lds16(sg[i] + (s + 2) * 64, ((s & 1) ? dg1 : dg0)[i]);
    }
  }

  // residual add; keep new x values in acc
#pragma unroll
  for (int mt = 0; mt < 4; ++mt)
#pragma unroll
    for (int nt = 0; nt < 4; ++nt)
#pragma unroll
      for (int r = 0; r < 4; ++r) {
        const size_t idx = (size_t)(m_blk + mt * 16 + quad * 4 + r) * DIM
                           + n0w + nt * 16 + ln16;
        const float v = x[idx] + acc[mt][nt][r];
        acc[mt][nt][r] = v;
        x[idx] = v;
      }

  if (DO_LN) {
    float2* red = (float2*)As[0];   // all As reads completed in-loop
#pragma unroll
    for (int mt = 0; mt < 4; ++mt)
#pragma unroll
      for (int r = 0; r < 4; ++r) {
        float s = 0.f, s2 = 0.f;
#pragma unroll
        for (int nt = 0; nt < 4; ++nt) {
          const float v = acc[mt][nt][r];
          s += v; s2 += v * v;
        }
#pragma unroll
        for (int off = 1; off < 16; off <<= 1) {
          s  += __shfl_xor(s, off, 64);
          s2 += __shfl_xor(s2, off, 64);
        }
        if (ln16 == 0)
          red[(mt * 16 + quad * 4 + r) * 4 + w] = float2{s, s2};
      }
    // red writes visible; no vmcnt drain needed (x ops are private)
    asm volatile("s_waitcnt lgkmcnt(0)" ::: "memory");
    __builtin_amdgcn_s_barrier();

    float gv[4], bv[4];
#pragma unroll
    for (int nt = 0; nt < 4; ++nt) {
      gv[nt] = lng[n0w + nt * 16 + ln16];
      bv[nt] = lnb[n0w + nt * 16 + ln16];
    }
#pragma unroll
    for (int mt = 0; mt < 4; ++mt)
#pragma unroll
      for (int r = 0; r < 4; ++r) {
        const int row = mt * 16 + quad * 4 + r;
        const float2 t0 = red[row * 4 + 0];
        const float2 t1 = red[row * 4 + 1];
        const float2 t2 = red[row * 4 + 2];
        const float2 t3 = red[row * 4 + 3];
        const float s  = (t0.x + t1.x) + (t2.x + t3.x);
        const float s2 = (t0.y + t1.y) + (t2.y + t3.y);
        const float mu = s * (1.0f / DIM);
        const float var = s2 * (1.0f / DIM) - mu * mu;
        const float rstd = rsqrtf(var + 1e-5f);
#pragma unroll
        for (int nt = 0; nt < 4; ++nt)
          xn[(size_t)(m_blk + row) * DIM + n0w + nt * 16 + ln16] =
              f2bf((acc[mt][nt][r] - mu) * rstd * gv[nt] + bv[nt]);
      }
  }
}

// ---- FUSED: attn-out projection + residual + LN + FF1 GEGLU -> y ----
// Phase 1 = gemm_res_ln<256> structure (dbuf, __syncthreads; proven). LN
// result -> LDS xn tile (swizzled). Phase 2: W_ff1 16KB slabs with counted
// vmcnt(4) raw barriers — prefetch of slab cs+2 stays in flight.
__global__ void __launch_bounds__(256, 2)
fused_out_ff1(const short* __restrict__ A, const short* __restrict__ W,
              float* __restrict__ x, const float* __restrict__ lng,
              const float* __restrict__ lnb, const short* __restrict__ wff,
              short* __restrict__ y) {
  __shared__ short As[2][64 * 64];
  __shared__ short Bs[2][256 * 64];
  const int tid = threadIdx.x;
  const int lane = tid & 63;
  const int w = tid >> 6;              // 0..3
  const int ln16 = lane & 15;
  const int quad = lane >> 4;
  const int m_blk = blockIdx.x * 64;
  const int n0w = w * 64;
  const int srow = lane >> 3;
  const int swz = (lane & 7) ^ srow;

  // ---------- phase 1: out-proj GEMM (K=256), r13 structure ----------
  const short* sg[10];
  short* dg0[10];
  short* dg1[10];
#pragma unroll
  for (int i = 0; i < 10; ++i) {
    const int grp = w + i * 4;
    if (grp < 8) {
      sg[i] = A + (size_t)(m_blk + grp * 8 + srow) * DIM + swz * 8;
      dg0[i] = &As[0][grp * 512];
      dg1[i] = &As[1][grp * 512];
    } else {
      const int gb = grp - 8;
      sg[i] = W + (size_t)(gb * 8 + srow) * DIM + swz * 8;
      dg0[i] = &Bs[0][gb * 512];
      dg1[i] = &Bs[1][gb * 512];
    }
  }

  f32x4 acc[4][4] = {};
#pragma unroll
  for (int i = 0; i < 10; ++i) gl_lds16(sg[i], dg0[i]);
  __syncthreads();

#pragma unroll
  for (int s = 0; s < 4; ++s) {
    if (s + 1 < 4) {
#pragma unroll
      for (int i = 0; i < 10; ++i)
        gl_lds16(sg[i] + (s + 1) * 64, ((s & 1) ? dg0 : dg1)[i]);
    }
    const short* Ac = (s & 1) ? As[1] : As[0];
    const short* Bc = (s & 1) ? Bs[1] : Bs[0];
    s16x8 af[2][4], bf[2][4];
#pragma unroll
    for (int kh = 0; kh < 2; ++kh) {
#pragma unroll
      for (int mt = 0; mt < 4; ++mt)
        af[kh][mt] = fragld(Ac, mt * 16 + ln16, kh * 4 + quad);
#pragma unroll
      for (int nt = 0; nt < 4; ++nt)
        bf[kh][nt] = fragld(Bc, n0w + nt * 16 + ln16, kh * 4 + quad);
    }
#pragma unroll
    for (int kh = 0; kh < 2; ++kh)
#pragma unroll
      for (int mt = 0; mt < 4; ++mt)
#pragma unroll
        for (int nt = 0; nt < 4; ++nt)
          acc[mt][nt] = __builtin_amdgcn_mfma_f32_16x16x32_bf16(af[kh][mt], bf[kh][nt], acc[mt][nt], 0, 0, 0);
    __syncthreads();
  }

  // W_ff1 staging geometry (phase 2); stage slabs 0,1 now — they land under
  // the residual/LN epilogue (raw barriers below do NOT drain vmcnt).
  short* const xnl = &Bs[0][0];        // 64 x 256 swizzled xn tile (32KB)
  short* const Wsl = &Bs[1][0];        // 2 x 16KB W slab buffers
  int wbase[4];
#pragma unroll
  for (int i = 0; i < 4; ++i) {
    const int grp = w + i * 4;
    const int half = grp >> 3;
    wbase[i] = (half * FFP + (grp & 7) * 8 + srow) * DIM + swz * 8;
  }
  auto stage2 = [&](int cs2) {
    const int c2 = cs2 >> 2, s2 = cs2 & 3;
    short* db = Wsl + ((cs2 & 1) ? 8192 : 0);
#pragma unroll
    for (int i = 0; i < 4; ++i)
      gl_lds16(wff + wbase[i] + c2 * (64 * DIM) + s2 * 64, db + (w + i * 4) * 512);
  };
  stage2(0);
  stage2(1);

  // residual add; keep new x values in acc
#pragma unroll
  for (int mt = 0; mt < 4; ++mt)
#pragma unroll
    for (int nt = 0; nt < 4; ++nt)
#pragma unroll
      for (int r = 0; r < 4; ++r) {
        const size_t idx = (size_t)(m_blk + mt * 16 + quad * 4 + r) * DIM
                           + n0w + nt * 16 + ln16;
        const float v = x[idx] + acc[mt][nt][r];
        acc[mt][nt][r] = v;
        x[idx] = v;
      }

  // LN reduce (red in As[0]; all As reads done at final phase-1 barrier)
  {
    float2* red = (float2*)As[0];
#pragma unroll
    for (int mt = 0; mt < 4; ++mt)
#pragma unroll
      for (int r = 0; r < 4; ++r) {
        float s = 0.f, s2 = 0.f;
#pragma unroll
        for (int nt = 0; nt < 4; ++nt) {
          const float v = acc[mt][nt][r];
          s += v; s2 += v * v;
        }
#pragma unroll
        for (int off = 1; off < 16; off <<= 1) {
          s  += __shfl_xor(s, off, 64);
          s2 += __shfl_xor(s2, off, 64);
        }
        if (ln16 == 0)
          red[(mt * 16 + quad * 4 + r) * 4 + w] = float2{s, s2};
      }
    asm volatile("s_waitcnt lgkmcnt(0)" ::: "memory");   // red visible
    __builtin_amdgcn_s_barrier();

    float gv[4], bv[4];
#pragma unroll
    for (int nt = 0; nt < 4; ++nt) {
      gv[nt] = lng[n0w + nt * 16 + ln16];
      bv[nt] = lnb[n0w + nt * 16 + ln16];
    }
    // LN result -> LDS xn tile, stored so fragld(xnl + s*4096, row, g) works:
    // sub-tile s=col>>6, pos ((col&63)>>3 ^ (row&7))*8 + (col&7)
#pragma unroll
    for (int mt = 0; mt < 4; ++mt)
#pragma unroll
      for (int r = 0; r < 4; ++r) {
        const int row = mt * 16 + quad * 4 + r;
        const float2 t0 = red[row * 4 + 0];
        const float2 t1 = red[row * 4 + 1];
        const float2 t2 = red[row * 4 + 2];
        const float2 t3 = red[row * 4 + 3];
        const float s  = (t0.x + t1.x) + (t2.x + t3.x);
        const float s2 = (t0.y + t1.y) + (t2.y + t3.y);
        const float mu = s * (1.0f / DIM);
        const float var = s2 * (1.0f / DIM) - mu * mu;
        const float rstd = rsqrtf(var + 1e-5f);
#pragma unroll
        for (int nt = 0; nt < 4; ++nt) {
          const int colin = nt * 16 + ln16;          // 0..63 within sub-tile w
          const int pos = ((colin >> 3) ^ (row & 7)) * 8 + (colin & 7);
          xnl[w * 4096 + row * 64 + pos] =
              f2bf((acc[mt][nt][r] - mu) * rstd * gv[nt] + bv[nt]);
        }
      }
  }
  asm volatile("s_waitcnt lgkmcnt(0)" ::: "memory");     // xnl visible
  __builtin_amdgcn_s_barrier();

  // ---------- phase 2: FF1 GEGLU, 11 chunks x 4 K-slabs, counted vmcnt ----------
  f32x4 aA[4], aG[4];
  for (int cs = 0; cs < 44; ++cs) {
    const int c = cs >> 2, s = cs & 3;
    // slab cs ready when only slab cs+1's 4 loads (+ younger stores) remain
    if (cs < 43) asm volatile("s_waitcnt vmcnt(4)" ::: "memory");
    else         asm volatile("s_waitcnt vmcnt(0)" ::: "memory");
    __builtin_amdgcn_s_barrier();
    if (s == 0) {
#pragma unroll
      for (int mt = 0; mt < 4; ++mt) { aA[mt] = f32x4{0.f,0.f,0.f,0.f}; aG[mt] = f32x4{0.f,0.f,0.f,0.f}; }
    }
    const short* Wb = Wsl + ((cs & 1) ? 8192 : 0);
    const short* Xs = xnl + s * 4096;
    s16x8 af[2][4], wa[2], wg[2];
#pragma unroll
    for (int kh = 0; kh < 2; ++kh) {
#pragma unroll
      for (int mt = 0; mt < 4; ++mt)
        af[kh][mt] = fragld(Xs, mt * 16 + ln16, kh * 4 + quad);
      wa[kh] = fragld(Wb, w * 16 + ln16, kh * 4 + quad);
      wg[kh] = fragld(Wb, 64 + w * 16 + ln16, kh * 4 + quad);
    }
#pragma unroll
    for (int kh = 0; kh < 2; ++kh)
#pragma unroll
      for (int mt = 0; mt < 4; ++mt) {
        aA[mt] = __builtin_amdgcn_mfma_f32_16x16x32_bf16(af[kh][mt], wa[kh], aA[mt], 0, 0, 0);
        aG[mt] = __builtin_amdgcn_mfma_f32_16x16x32_bf16(af[kh][mt], wg[kh], aG[mt], 0, 0, 0);
      }
    // this wave's LDS reads complete; barrier -> safe to overwrite slab buffer
    asm volatile("s_waitcnt lgkmcnt(0)" ::: "memory");
    __builtin_amdgcn_s_barrier();
    if (cs + 2 < 44) stage2(cs + 2);
    if (s == 3) {
      const int col = c * 64 + w * 16 + ln16;
#pragma unroll
      for (int mt = 0; mt < 4; ++mt)
#pragma unroll
        for (int r = 0; r < 4; ++r)
          y[(size_t)(m_blk + mt * 16 + quad * 4 + r) * FFP + col] =
              f2bf(aA[mt][r] * gelu_as(aG[mt][r]));
    }
  }
}

// -------- QKV GEMM (BK=64 swizzled, 2 m-tiles/block): Q,K head-major; V permuted f16 --------
__global__ void __launch_bounds__(256)
gemm_qkv(const short* __restrict__ A, const short* __restrict__ W,
         short* __restrict__ qh, short* __restrict__ kh_, _Float16* __restrict__ vp) {
  __shared__ short As[128 * 64];
  __shared__ short Bs[128 * 64];
  const int tid = threadIdx.x;
  const int lane = tid & 63;
  const int w = tid >> 6;
  const int ln16 = lane & 15;
  const int quad = lane >> 4;
  const int m_blk0 = blockIdx.x * 256;     // two 128-row tiles
  const int n_blk = blockIdx.y * 128;
  const int m0w = (w & 1) * 64;
  const int n0w = (w >> 1) * 64;
  const int srow = lane >> 3;
  const int swz = (lane & 7) ^ srow;

  int aoff[4];
  const short* bsrc[4];
  short* dst[8];
#pragma unroll
  for (int i = 0; i < 8; ++i) {
    const int grp = w + i * 4;
    if (i < 4) {
      aoff[i] = (grp * 8 + srow) * DIM + swz * 8;
      dst[i] = As + grp * 512;
    } else {
      const int gb = grp - 16;
      bsrc[i - 4] = W + (size_t)(n_blk + gb * 8 + srow) * DIM + swz * 8;
      dst[i] = Bs + gb * 512;
    }
  }

  auto stage = [&](int t2, int s2) {
    const short* At = A + (size_t)(m_blk0 + t2 * 128) * DIM + s2 * 64;
#pragma unroll
    for (int i = 0; i < 4; ++i) gl_lds16(At + aoff[i], dst[i]);
#pragma unroll
    for (int i = 0; i < 4; ++i) gl_lds16(bsrc[i] + s2 * 64, dst[i + 4]);
  };

  stage(0, 0);

#pragma unroll
  for (int t = 0; t < 2; ++t) {
    f32x4 acc[4][4] = {};
#pragma unroll
    for (int s = 0; s < 4; ++s) {
      __syncthreads();
      s16x8 af[2][4], bf[2][4];
#pragma unroll
      for (int kh = 0; kh < 2; ++kh) {
#pragma unroll
        for (int mt = 0; mt < 4; ++mt)
          af[kh][mt] = fragld(As, m0w + mt * 16 + ln16, kh * 4 + quad);
#pragma unroll
        for (int nt = 0; nt < 4; ++nt)
          bf[kh][nt] = fragld(Bs, n0w + nt * 16 + ln16, kh * 4 + quad);
      }
#pragma unroll
      for (int kh = 0; kh < 2; ++kh)
#pragma unroll
        for (int mt = 0; mt < 4; ++mt)
#pragma unroll
          for (int nt = 0; nt < 4; ++nt)
            acc[mt][nt] = __builtin_amdgcn_mfma_f32_16x16x32_bf16(af[kh][mt], bf[kh][nt], acc[mt][nt], 0, 0, 0);
      if (!(t == 1 && s == 3)) {
        __syncthreads();
        if (s == 3) stage(t + 1, 0);
        else        stage(t, s + 1);
      }
    }

#pragma unroll
    for (int mt = 0; mt < 4; ++mt) {
      const int m = m_blk0 + t * 128 + m0w + mt * 16 + quad * 4;
      const int bb = m >> 12;
      const int n = m & 4095;
#pragma unroll
      for (int nt = 0; nt < 4; ++nt) {
        const int f = n_blk + n0w + nt * 16;
        if (f < 512) {
          const int ff = f & 255;
          short* dstp = (f < 256 ? qh : kh_)
                       + ((size_t)(bb * 8 + (ff >> 5)) * SEQ + n) * 32 + (ff & 16) + ln16;
#pragma unroll
          for (int r = 0; r < 4; ++r) dstp[r * 32] = f2bf(acc[mt][nt][r]);
        } else {
          const int ff = f - 512;
          const int h = ff >> 5;
          const int d = (ff & 16) + ln16;
          const int within = n & 31;
          const int pos = (n & ~31) + ((within & 12) << 1) + ((within >> 4) << 2);
          f16x4 o;
#pragma unroll
          for (int r = 0; r < 4; ++r) o[r] = (_Float16)acc[mt][nt][r];
          *(f16x4*)(vp + ((size_t)(bb * 8 + h) * 32 + d) * SEQ + pos) = o;
        }
      }
    }
  }
}

// ---------------- Local attention: wave = half-window (4 q-tiles), prefetched ----------------
__global__ void __launch_bounds__(256)
attn_kernel(const short* __restrict__ qh, const short* __restrict__ kh,
            const _Float16* __restrict__ vp, short* __restrict__ out) {
  const int blk = blockIdx.x;              // 1024 blocks
  const int lane = threadIdx.x & 63;
  const int wid = threadIdx.x >> 6;
  const int ln16 = lane & 15;
  const int quad = lane >> 4;

  const int w = (blk & 15) * 2 + (wid >> 1);
  const int h = (blk >> 4) & 7;
  const int b = blk >> 7;
  const int plane = b * 8 + h;
  const int tok0 = w * 128 + (wid & 1) * 64;
  const int ktok = w * 128 - 128;
  const int c0 = (w == 0) ? 4 : 0;
  const int c1 = (w == NWIN - 1) ? 8 : 12;

  const short* qp = qh + ((size_t)plane * SEQ + tok0) * 32;
  s16x8 qf[4];
#pragma unroll
  for (int qi = 0; qi < 4; ++qi)
    qf[qi] = *(const s16x8*)(qp + (qi * 16 + ln16) * 32 + quad * 8);

  const short* kp = kh + ((size_t)plane * SEQ + ktok) * 32;
  const _Float16* vb = vp + ((size_t)plane * 32 + ln16) * SEQ + ktok;

  float lsum[4] = {0.f, 0.f, 0.f, 0.f};
  f32x4 ot[4][2] = {};

  s16x8 kc0 = *(const s16x8*)(kp + (c0 * 32 + ln16) * 32 + quad * 8);
  s16x8 kc1 = *(const s16x8*)(kp + (c0 * 32 + 16 + ln16) * 32 + quad * 8);
  f16x8 vc0 = *(const f16x8*)(vb + c0 * 32 + quad * 8);
  f16x8 vc1 = *(const f16x8*)(vb + (size_t)16 * SEQ + c0 * 32 + quad * 8);

  for (int c = c0; c < c1; ++c) {
    const int cn = (c + 1 < c1) ? c + 1 : c;
    s16x8 kn0 = *(const s16x8*)(kp + (cn * 32 + ln16) * 32 + quad * 8);
    s16x8 kn1 = *(const s16x8*)(kp + (cn * 32 + 16 + ln16) * 32 + quad * 8);
    f16x8 vn0 = *(const f16x8*)(vb + cn * 32 + quad * 8);
    f16x8 vn1 = *(const f16x8*)(vb + (size_t)16 * SEQ + cn * 32 + quad * 8);

    const f16x4 v00 = __builtin_shufflevector(vc0, vc0, 0, 1, 2, 3);
    const f16x4 v10 = __builtin_shufflevector(vc0, vc0, 4, 5, 6, 7);
    const f16x4 v01 = __builtin_shufflevector(vc1, vc1, 0, 1, 2, 3);
    const f16x4 v11 = __builtin_shufflevector(vc1, vc1, 4, 5, 6, 7);

#pragma unroll
    for (int qi = 0; qi < 4; ++qi) {
      const f32x4 z = {0.f, 0.f, 0.f, 0.f};
      f32x4 st0 = __builtin_amdgcn_mfma_f32_16x16x32_bf16(kc0, qf[qi], z, 0, 0, 0);
      f32x4 st1 = __builtin_amdgcn_mfma_f32_16x16x32_bf16(kc1, qf[qi], z, 0, 0, 0);
      float p[8];
#pragma unroll
      for (int r = 0; r < 4; ++r) {
        p[r]     = fast_exp2(st0[r] * ATT_SCALE_LOG2E);
        p[4 + r] = fast_exp2(st1[r] * ATT_SCALE_LOG2E);
      }
      lsum[qi] += ((p[0] + p[1]) + (p[2] + p[3])) + ((p[4] + p[5]) + (p[6] + p[7]));
      f16x4 pa, pb;
#pragma unroll
      for (int r = 0; r < 4; ++r) { pa[r] = (_Float16)p[r]; pb[r] = (_Float16)p[4 + r]; }
      ot[qi][0] = __builtin_amdgcn_mfma_f32_16x16x16f16(pa, v00, ot[qi][0], 0, 0, 0);
      ot[qi][1] = __builtin_amdgcn_mfma_f32_16x16x16f16(pa, v01, ot[qi][1], 0, 0, 0);
      ot[qi][0] = __builtin_amdgcn_mfma_f32_16x16x16f16(pb, v10, ot[qi][0], 0, 0, 0);
      ot[qi][1] = __builtin_amdgcn_mfma_f32_16x16x16f16(pb, v11, ot[qi][1], 0, 0, 0);
    }
    kc0 = kn0; kc1 = kn1; vc0 = vn0; vc1 = vn1;
  }

#pragma unroll
  for (int qi = 0; qi < 4; ++qi) {
    float l = lsum[qi];
    l += __shfl_xor(l, 16, 64);
    l += __shfl_xor(l, 32, 64);
    const float inv = 1.0f / l;
#pragma unroll
    for (int dt = 0; dt < 2; ++dt)
#pragma unroll
      for (int r = 0; r < 4; ++r)
        out[(size_t)(b * SEQ + tok0 + qi * 16 + quad * 4 + r) * DIM
            + h * DHEAD + dt * 16 + ln16] = f2bf(ot[qi][dt][r] * inv);
  }
}

// ---------------- merged weight conversion fp32 -> bf16 (with FF padding) ----------------
__global__ void cvt_all(const float* __restrict__ qkv_w, const float* __restrict__ out_w,
                        const float* __restrict__ ff_w1, const float* __restrict__ ff_w2,
                        short* __restrict__ wqkv, short* __restrict__ wout,
                        short* __restrict__ wff1, short* __restrict__ wff2) {
  int i = blockIdx.x * 256 + threadIdx.x;
  if (i < 786432) { wqkv[i] = f2bf(qkv_w[i]); return; }
  i -= 786432;
  if (i < 262144) { wout[i] = f2bf(out_w[i]); return; }
  i -= 262144;
  if (i < 1441792) {
    const int c = i & 255;
    const int rl = i >> 8;
    const int l = rl / 1408;
    const int r = rl - l * 1408;
    const int half = r / FFP;
    const int rr = r - half * FFP;
    const float v = (rr < 682) ? ff_w1[((size_t)(l * 1364 + half * 682 + rr)) * 256 + c] : 0.0f;
    wff1[i] = f2bf(v);
    return;
  }
  i -= 1441792;
  if (i < 720896) {
    const int c = i % FFP;
    const int t = i / FFP;
    const float v = (c < 682) ? ff_w2[(size_t)t * 682 + c] : 0.0f;
    wff2[i] = f2bf(v);
  }
}

// ---------------- driver ----------------
extern "C" void kernel_launch(void* const* d_in, const int* in_sizes, int n_in,
                              void* d_out, int out_size, void* d_ws, size_t ws_size,
                              hipStream_t stream) {
  const float* x0    = (const float*)d_in[0];
  const float* ln1_g = (const float*)d_in[2];
  const float* ln1_b = (const float*)d_in[3];
  const float* qkv_w = (const float*)d_in[4];
  const float* out_w = (const float*)d_in[5];
  const float* ln2_g = (const float*)d_in[6];
  const float* ln2_b = (const float*)d_in[7];
  const float* ff_w1 = (const float*)d_in[8];
  const float* ff_w2 = (const float*)d_in[9];
  float* x = (float*)d_out;

  char* ws = (char*)d_ws;
  short* wqkv = (short*)(ws);                    //  4*768*256 bf16
  short* wout = (short*)(ws + 1572864);          //  4*256*256
  short* wff1 = (short*)(ws + 2097152);          //  4*1408*256
  short* wff2 = (short*)(ws + 4980736);          //  4*256*704
  short* xn   = (short*)(ws + 6422528);          //  32768*256 (LN out / attn out)
  short*    qhb = (short*)(ws + 23199744);                 // 16.8MB qkv->attn
  short*    khb = (short*)(ws + 23199744 + 16777216);      // 16.8MB qkv->attn
  _Float16* vpb = (_Float16*)(ws + 23199744 + 33554432);   // 16.8MB qkv->attn
  short*    yb  = (short*)(ws + 23199744);                 // 46.1MB fused->ff2 (disjoint lifetime)

  copy_ln<<<8192, 256, 0, stream>>>(x0, ln1_g, ln1_b, x, xn);
  cvt_all<<<12544, 256, 0, stream>>>(qkv_w, out_w, ff_w1, ff_w2, wqkv, wout, wff1, wff2);

  for (int l = 0; l < 4; ++l) {
    gemm_qkv<<<dim3(128, 6), 256, 0, stream>>>(
        xn, wqkv + (size_t)l * 768 * DIM, qhb, khb, vpb);
    attn_kernel<<<1024, 256, 0, stream>>>(qhb, khb, vpb, xn);
    fused_out_ff1<<<512, 256, 0, stream>>>(
        xn, wout + (size_t)l * DIM * DIM, x,
        ln2_g + l * DIM, ln2_b + l * DIM,
        wff1 + (size_t)l * 2 * FFP * DIM, yb);
    if (l < 3)
      gemm_res_ln<FFP, true><<<512, 256, 0, stream>>>(
          yb, wff2 + (size_t)l * DIM * FFP, x,
          ln1_g + (l + 1) * DIM, ln1_b + (l + 1) * DIM, xn);
    else
      gemm_res_ln<FFP, false><<<512, 256, 0, stream>>>(
          yb, wff2 + (size_t)l * DIM * FFP, x, nullptr, nullptr, nullptr);
  }
}

// Round 9
// 695.920 us; speedup vs baseline: 1.1677x; 1.0192x over previous
//
#include <hip/hip_runtime.h>

// LocalEncoder on MI355X — round 16: A-fragments hoisted to registers in
// fused phase 2. r15 post-mortem: counted vmcnt neutral -> barrier drain was
// not the stall. Arithmetic: phase 2's 12 ds_read_b128/wave/slab (8 of them
// re-reading the SAME xn tile every chunk, 11x) ~= 52k cyc/CU of LDS reads,
// ~1/3 of the kernel. Fix: afr[4][2][4] registers (128 VGPR, free — occupancy
// is LDS-bound at 2 blocks/CU) loaded once; inner loop reads only wa/wg
// (4 b128/slab). Loop restructured c-outer / s-inner-unrolled so all afr
// indices and buffer parity (s&1) are compile-time (no scratch). Everything
// else byte-identical to r15 (709.3us best).

#define DIM 256
#define DHEAD 32
#define NWIN 32
#define SEQ 4096
#define TOKENS 32768
#define FFP 704
#define ATT_SCALE_LOG2E 0.25501818642228136f

typedef __attribute__((ext_vector_type(4))) float f32x4;
typedef __attribute__((ext_vector_type(4))) short s16x4;
typedef __attribute__((ext_vector_type(8))) short s16x8;
typedef __attribute__((ext_vector_type(4))) _Float16 f16x4;
typedef __attribute__((ext_vector_type(8))) _Float16 f16x8;

__device__ __forceinline__ short f2bf(float f) {
  unsigned int u = __float_as_uint(f);
  u += 0x7fffu + ((u >> 16) & 1u);
  return (short)(u >> 16);
}

__device__ __forceinline__ float fast_exp2(float x) {
#if __has_builtin(__builtin_amdgcn_exp2f)
  return __builtin_amdgcn_exp2f(x);
#else
  return __expf(x * 0.6931471805599453f);
#endif
}

// A&S 7.1.26 erf-based exact GELU: |erf err| < 1.5e-7 (below bf16 rounding).
__device__ __forceinline__ float gelu_as(float g) {
  const float z = fabsf(g) * 0.70710678118654752440f;
#if __has_builtin(__builtin_amdgcn_rcpf)
  const float t = __builtin_amdgcn_rcpf(fmaf(0.3275911f, z, 1.0f));
#else
  const float t = 1.0f / fmaf(0.3275911f, z, 1.0f);
#endif
  const float e = fast_exp2(-z * z * 1.4426950408889634f);
  const float poly = t * fmaf(t, fmaf(t, fmaf(t, fmaf(t, 1.061405429f,
                     -1.453152027f), 1.421413741f), -0.284496736f), 0.254829592f);
  const float erfv = fmaf(-poly, e, 1.0f);
  const float se = (g < 0.0f) ? -erfv : erfv;
  return 0.5f * g * (1.0f + se);
}

__device__ __forceinline__ void gl_lds16(const short* g, short* l) {
  __builtin_amdgcn_global_load_lds(
      (const __attribute__((address_space(1))) void*)g,
      (__attribute__((address_space(3))) void*)l, 16, 0, 0);
}

// fragment read from a BK=64 swizzled tile: 16B block g (= kh*4+quad) of `row`
__device__ __forceinline__ s16x8 fragld(const short* lds, int row, int g) {
  return *(const s16x8*)(lds + row * 64 + ((g ^ (row & 7)) << 3));
}

// ---------------- copy + LayerNorm: x0 fp32 -> x fp32 copy + xn bf16 ----------------
__global__ void __launch_bounds__(256)
copy_ln(const float* __restrict__ x0, const float* __restrict__ gw,
        const float* __restrict__ bw, float* __restrict__ x, short* __restrict__ xn) {
  const int row = blockIdx.x * 4 + (threadIdx.x >> 6);
  const int lane = threadIdx.x & 63;
  const f32x4 v = *(const f32x4*)(x0 + (size_t)row * DIM + lane * 4);
  *(f32x4*)(x + (size_t)row * DIM + lane * 4) = v;
  float s = v[0] + v[1] + v[2] + v[3];
  float s2 = v[0]*v[0] + v[1]*v[1] + v[2]*v[2] + v[3]*v[3];
#pragma unroll
  for (int off = 32; off > 0; off >>= 1) {
    s  += __shfl_xor(s, off, 64);
    s2 += __shfl_xor(s2, off, 64);
  }
  const float mu = s * (1.0f / DIM);
  const float var = s2 * (1.0f / DIM) - mu * mu;
  const float rstd = rsqrtf(var + 1e-5f);
  const f32x4 gv = *(const f32x4*)(gw + lane * 4);
  const f32x4 bv = *(const f32x4*)(bw + lane * 4);
  s16x4 o;
#pragma unroll
  for (int j = 0; j < 4; ++j) o[j] = f2bf((v[j] - mu) * rstd * gv[j] + bv[j]);
  *(s16x4*)(xn + (size_t)row * DIM + lane * 4) = o;
}

// -------- Residual GEMM + fused next-LN (FF2 path): x += A.W^T; xn = LN(x) --------
// 256 threads, 4 waves; block tile 64 x 256, wave tile 64x64. BK=64, swizzled,
// dbuf LDS (80KB -> 2 blocks/CU). Counted-vmcnt raw barriers (r15).
template<int K, bool DO_LN>
__global__ void __launch_bounds__(256, 2)
gemm_res_ln(const short* __restrict__ A, const short* __restrict__ W,
            float* __restrict__ x, const float* __restrict__ lng,
            const float* __restrict__ lnb, short* __restrict__ xn) {
  __shared__ short As[2][64 * 64];
  __shared__ short Bs[2][256 * 64];
  const int tid = threadIdx.x;
  const int lane = tid & 63;
  const int w = tid >> 6;              // 0..3
  const int ln16 = lane & 15;
  const int quad = lane >> 4;
  const int m_blk = blockIdx.x * 64;
  const int n0w = w * 64;
  const int srow = lane >> 3;
  const int swz = (lane & 7) ^ srow;

  // 40 staging groups of 8 rows: 0..7 = A, 8..39 = B. Wave w: grp = w + i*4.
  const short* sg[10];
  short* dg0[10];
  short* dg1[10];
#pragma unroll
  for (int i = 0; i < 10; ++i) {
    const int grp = w + i * 4;
    if (grp < 8) {
      sg[i] = A + (size_t)(m_blk + grp * 8 + srow) * K + swz * 8;
      dg0[i] = &As[0][grp * 512];
      dg1[i] = &As[1][grp * 512];
    } else {
      const int gb = grp - 8;
      sg[i] = W + (size_t)(gb * 8 + srow) * K + swz * 8;
      dg0[i] = &Bs[0][gb * 512];
      dg1[i] = &Bs[1][gb * 512];
    }
  }

  constexpr int NS = K / 64;
  f32x4 acc[4][4] = {};

  // prologue: stage slabs 0 and 1 (buffers 0, 1)
#pragma unroll
  for (int i = 0; i < 10; ++i) gl_lds16(sg[i], dg0[i]);
#pragma unroll
  for (int i = 0; i < 10; ++i) gl_lds16(sg[i] + 64, dg1[i]);

#pragma unroll
  for (int s = 0; s < NS; ++s) {
    // slab s complete when only slab s+1's 10 loads may remain in flight
    if (s + 1 < NS) asm volatile("s_waitcnt vmcnt(10)" ::: "memory");
    else            asm volatile("s_waitcnt vmcnt(0)" ::: "memory");
    __builtin_amdgcn_s_barrier();
    const short* Ac = (s & 1) ? As[1] : As[0];
    const short* Bc = (s & 1) ? Bs[1] : Bs[0];
    s16x8 af[2][4], bf[2][4];
#pragma unroll
    for (int kh = 0; kh < 2; ++kh) {
#pragma unroll
      for (int mt = 0; mt < 4; ++mt)
        af[kh][mt] = fragld(Ac, mt * 16 + ln16, kh * 4 + quad);
#pragma unroll
      for (int nt = 0; nt < 4; ++nt)
        bf[kh][nt] = fragld(Bc, n0w + nt * 16 + ln16, kh * 4 + quad);
    }
#pragma unroll
    for (int kh = 0; kh < 2; ++kh)
#pragma unroll
      for (int mt = 0; mt < 4; ++mt)
#pragma unroll
        for (int nt = 0; nt < 4; ++nt)
          acc[mt][nt] = __builtin_amdgcn_mfma_f32_16x16x32_bf16(af[kh][mt], bf[kh][nt], acc[mt][nt], 0, 0, 0);
    // all this wave's LDS reads are complete; barrier -> safe to overwrite buf
    asm volatile("s_waitcnt lgkmcnt(0)" ::: "memory");
    __builtin_amdgcn_s_barrier();
    if (s + 2 < NS) {
#pragma unroll
      for (int i = 0; i < 10; ++i)
        gl_lds16(sg[i] + (s + 2) * 64, ((s & 1) ? dg1 : dg0)[i]);
    }
  }

  // residual add; keep new x values in acc
#pragma unroll
  for (int mt = 0; mt < 4; ++mt)
#pragma unroll
    for (int nt = 0; nt < 4; ++nt)
#pragma unroll
      for (int r = 0; r < 4; ++r) {
        const size_t idx = (size_t)(m_blk + mt * 16 + quad * 4 + r) * DIM
                           + n0w + nt * 16 + ln16;
        const float v = x[idx] + acc[mt][nt][r];
        acc[mt][nt][r] = v;
        x[idx] = v;
      }

  if (DO_LN) {
    float2* red = (float2*)As[0];   // all As reads completed in-loop
#pragma unroll
    for (int mt = 0; mt < 4; ++mt)
#pragma unroll
      for (int r = 0; r < 4; ++r) {
        float s = 0.f, s2 = 0.f;
#pragma unroll
        for (int nt = 0; nt < 4; ++nt) {
          const float v = acc[mt][nt][r];
          s += v; s2 += v * v;
        }
#pragma unroll
        for (int off = 1; off < 16; off <<= 1) {
          s  += __shfl_xor(s, off, 64);
          s2 += __shfl_xor(s2, off, 64);
        }
        if (ln16 == 0)
          red[(mt * 16 + quad * 4 + r) * 4 + w] = float2{s, s2};
      }
    // red writes visible; no vmcnt drain needed (x ops are private)
    asm volatile("s_waitcnt lgkmcnt(0)" ::: "memory");
    __builtin_amdgcn_s_barrier();

    float gv[4], bv[4];
#pragma unroll
    for (int nt = 0; nt < 4; ++nt) {
      gv[nt] = lng[n0w + nt * 16 + ln16];
      bv[nt] = lnb[n0w + nt * 16 + ln16];
    }
#pragma unroll
    for (int mt = 0; mt < 4; ++mt)
#pragma unroll
      for (int r = 0; r < 4; ++r) {
        const int row = mt * 16 + quad * 4 + r;
        const float2 t0 = red[row * 4 + 0];
        const float2 t1 = red[row * 4 + 1];
        const float2 t2 = red[row * 4 + 2];
        const float2 t3 = red[row * 4 + 3];
        const float s  = (t0.x + t1.x) + (t2.x + t3.x);
        const float s2 = (t0.y + t1.y) + (t2.y + t3.y);
        const float mu = s * (1.0f / DIM);
        const float var = s2 * (1.0f / DIM) - mu * mu;
        const float rstd = rsqrtf(var + 1e-5f);
#pragma unroll
        for (int nt = 0; nt < 4; ++nt)
          xn[(size_t)(m_blk + row) * DIM + n0w + nt * 16 + ln16] =
              f2bf((acc[mt][nt][r] - mu) * rstd * gv[nt] + bv[nt]);
      }
  }
}

// ---- FUSED: attn-out projection + residual + LN + FF1 GEGLU -> y ----
// Phase 1 = gemm_res_ln<256> structure. LN result -> LDS xn tile (swizzled),
// then ALL A-fragments hoisted to registers afr[4][2][4] (128 VGPR). Phase 2:
// W_ff1 16KB slabs, counted vmcnt raw barriers; only 4 ds_read_b128/slab.
__global__ void __launch_bounds__(256, 2)
fused_out_ff1(const short* __restrict__ A, const short* __restrict__ W,
              float* __restrict__ x, const float* __restrict__ lng,
              const float* __restrict__ lnb, const short* __restrict__ wff,
              short* __restrict__ y) {
  __shared__ short As[2][64 * 64];
  __shared__ short Bs[2][256 * 64];
  const int tid = threadIdx.x;
  const int lane = tid & 63;
  const int w = tid >> 6;              // 0..3
  const int ln16 = lane & 15;
  const int quad = lane >> 4;
  const int m_blk = blockIdx.x * 64;
  const int n0w = w * 64;
  const int srow = lane >> 3;
  const int swz = (lane & 7) ^ srow;

  // ---------- phase 1: out-proj GEMM (K=256), r13 structure ----------
  const short* sg[10];
  short* dg0[10];
  short* dg1[10];
#pragma unroll
  for (int i = 0; i < 10; ++i) {
    const int grp = w + i * 4;
    if (grp < 8) {
      sg[i] = A + (size_t)(m_blk + grp * 8 + srow) * DIM + swz * 8;
      dg0[i] = &As[0][grp * 512];
      dg1[i] = &As[1][grp * 512];
    } else {
      const int gb = grp - 8;
      sg[i] = W + (size_t)(gb * 8 + srow) * DIM + swz * 8;
      dg0[i] = &Bs[0][gb * 512];
      dg1[i] = &Bs[1][gb * 512];
    }
  }

  f32x4 acc[4][4] = {};
#pragma unroll
  for (int i = 0; i < 10; ++i) gl_lds16(sg[i], dg0[i]);
  __syncthreads();

#pragma unroll
  for (int s = 0; s < 4; ++s) {
    if (s + 1 < 4) {
#pragma unroll
      for (int i = 0; i < 10; ++i)
        gl_lds16(sg[i] + (s + 1) * 64, ((s & 1) ? dg0 : dg1)[i]);
    }
    const short* Ac = (s & 1) ? As[1] : As[0];
    const short* Bc = (s & 1) ? Bs[1] : Bs[0];
    s16x8 af[2][4], bf[2][4];
#pragma unroll
    for (int kh = 0; kh < 2; ++kh) {
#pragma unroll
      for (int mt = 0; mt < 4; ++mt)
        af[kh][mt] = fragld(Ac, mt * 16 + ln16, kh * 4 + quad);
#pragma unroll
      for (int nt = 0; nt < 4; ++nt)
        bf[kh][nt] = fragld(Bc, n0w + nt * 16 + ln16, kh * 4 + quad);
    }
#pragma unroll
    for (int kh = 0; kh < 2; ++kh)
#pragma unroll
      for (int mt = 0; mt < 4; ++mt)
#pragma unroll
        for (int nt = 0; nt < 4; ++nt)
          acc[mt][nt] = __builtin_amdgcn_mfma_f32_16x16x32_bf16(af[kh][mt], bf[kh][nt], acc[mt][nt], 0, 0, 0);
    __syncthreads();
  }

  // W_ff1 staging geometry (phase 2); stage slabs 0,1 now — they land under
  // the residual/LN epilogue (raw barriers below do NOT drain vmcnt).
  short* const xnl = &Bs[0][0];        // 64 x 256 swizzled xn tile (32KB)
  short* const Wsl = &Bs[1][0];        // 2 x 16KB W slab buffers
  int wbase[4];
#pragma unroll
  for (int i = 0; i < 4; ++i) {
    const int grp = w + i * 4;
    const int half = grp >> 3;
    wbase[i] = (half * FFP + (grp & 7) * 8 + srow) * DIM + swz * 8;
  }
  auto stage2 = [&](int cs2) {
    const int c2 = cs2 >> 2, s2 = cs2 & 3;
    short* db = Wsl + ((cs2 & 1) ? 8192 : 0);
#pragma unroll
    for (int i = 0; i < 4; ++i)
      gl_lds16(wff + wbase[i] + c2 * (64 * DIM) + s2 * 64, db + (w + i * 4) * 512);
  };
  stage2(0);
  stage2(1);

  // residual add; keep new x values in acc
#pragma unroll
  for (int mt = 0; mt < 4; ++mt)
#pragma unroll
    for (int nt = 0; nt < 4; ++nt)
#pragma unroll
      for (int r = 0; r < 4; ++r) {
        const size_t idx = (size_t)(m_blk + mt * 16 + quad * 4 + r) * DIM
                           + n0w + nt * 16 + ln16;
        const float v = x[idx] + acc[mt][nt][r];
        acc[mt][nt][r] = v;
        x[idx] = v;
      }

  // LN reduce (red in As[0]; all As reads done at final phase-1 barrier)
  {
    float2* red = (float2*)As[0];
#pragma unroll
    for (int mt = 0; mt < 4; ++mt)
#pragma unroll
      for (int r = 0; r < 4; ++r) {
        float s = 0.f, s2 = 0.f;
#pragma unroll
        for (int nt = 0; nt < 4; ++nt) {
          const float v = acc[mt][nt][r];
          s += v; s2 += v * v;
        }
#pragma unroll
        for (int off = 1; off < 16; off <<= 1) {
          s  += __shfl_xor(s, off, 64);
          s2 += __shfl_xor(s2, off, 64);
        }
        if (ln16 == 0)
          red[(mt * 16 + quad * 4 + r) * 4 + w] = float2{s, s2};
      }
    asm volatile("s_waitcnt lgkmcnt(0)" ::: "memory");   // red visible
    __builtin_amdgcn_s_barrier();

    float gv[4], bv[4];
#pragma unroll
    for (int nt = 0; nt < 4; ++nt) {
      gv[nt] = lng[n0w + nt * 16 + ln16];
      bv[nt] = lnb[n0w + nt * 16 + ln16];
    }
    // LN result -> LDS xn tile, stored so fragld(xnl + s*4096, row, g) works:
    // sub-tile s=col>>6, pos ((col&63)>>3 ^ (row&7))*8 + (col&7)
#pragma unroll
    for (int mt = 0; mt < 4; ++mt)
#pragma unroll
      for (int r = 0; r < 4; ++r) {
        const int row = mt * 16 + quad * 4 + r;
        const float2 t0 = red[row * 4 + 0];
        const float2 t1 = red[row * 4 + 1];
        const float2 t2 = red[row * 4 + 2];
        const float2 t3 = red[row * 4 + 3];
        const float s  = (t0.x + t1.x) + (t2.x + t3.x);
        const float s2 = (t0.y + t1.y) + (t2.y + t3.y);
        const float mu = s * (1.0f / DIM);
        const float var = s2 * (1.0f / DIM) - mu * mu;
        const float rstd = rsqrtf(var + 1e-5f);
#pragma unroll
        for (int nt = 0; nt < 4; ++nt) {
          const int colin = nt * 16 + ln16;          // 0..63 within sub-tile w
          const int pos = ((colin >> 3) ^ (row & 7)) * 8 + (colin & 7);
          xnl[w * 4096 + row * 64 + pos] =
              f2bf((acc[mt][nt][r] - mu) * rstd * gv[nt] + bv[nt]);
        }
      }
  }
  asm volatile("s_waitcnt lgkmcnt(0)" ::: "memory");     // xnl visible
  __builtin_amdgcn_s_barrier();

  // Hoist ALL A-fragments to registers (indices compile-time -> no scratch).
  // 4 slabs x 2 kh x 4 mt x 4 VGPR = 128 VGPR; occupancy is LDS-bound so free.
  s16x8 afr[4][2][4];
#pragma unroll
  for (int s = 0; s < 4; ++s)
#pragma unroll
    for (int kh = 0; kh < 2; ++kh)
#pragma unroll
      for (int mt = 0; mt < 4; ++mt)
        afr[s][kh][mt] = fragld(xnl + s * 4096, mt * 16 + ln16, kh * 4 + quad);

  // ---------- phase 2: FF1 GEGLU, 11 chunks x 4 K-slabs, counted vmcnt ----------
  for (int c = 0; c < 11; ++c) {
    f32x4 aA[4] = {}, aG[4] = {};
#pragma unroll
    for (int s = 0; s < 4; ++s) {      // compile-time s; buffer parity = s&1
      const int cs = c * 4 + s;
      // slab cs ready when only slab cs+1's 4 loads (+ younger ops) remain
      if (c == 10 && s == 3) asm volatile("s_waitcnt vmcnt(0)" ::: "memory");
      else                   asm volatile("s_waitcnt vmcnt(4)" ::: "memory");
      __builtin_amdgcn_s_barrier();
      const short* Wb = Wsl + ((s & 1) ? 8192 : 0);
      s16x8 wa[2], wg[2];
#pragma unroll
      for (int kh = 0; kh < 2; ++kh) {
        wa[kh] = fragld(Wb, w * 16 + ln16, kh * 4 + quad);
        wg[kh] = fragld(Wb, 64 + w * 16 + ln16, kh * 4 + quad);
      }
#pragma unroll
      for (int kh = 0; kh < 2; ++kh)
#pragma unroll
        for (int mt = 0; mt < 4; ++mt) {
          aA[mt] = __builtin_amdgcn_mfma_f32_16x16x32_bf16(afr[s][kh][mt], wa[kh], aA[mt], 0, 0, 0);
          aG[mt] = __builtin_amdgcn_mfma_f32_16x16x32_bf16(afr[s][kh][mt], wg[kh], aG[mt], 0, 0, 0);
        }
      // this wave's LDS reads complete; barrier -> safe to overwrite slab buf
      asm volatile("s_waitcnt lgkmcnt(0)" ::: "memory");
      __builtin_amdgcn_s_barrier();
      if (cs + 2 < 44) stage2(cs + 2);
    }
    const int col = c * 64 + w * 16 + ln16;
#pragma unroll
    for (int mt = 0; mt < 4; ++mt)
#pragma unroll
      for (int r = 0; r < 4; ++r)
        y[(size_t)(m_blk + mt * 16 + quad * 4 + r) * FFP + col] =
            f2bf(aA[mt][r] * gelu_as(aG[mt][r]));
  }
}

// -------- QKV GEMM (BK=64 swizzled, 2 m-tiles/block): Q,K head-major; V permuted f16 --------
__global__ void __launch_bounds__(256)
gemm_qkv(const short* __restrict__ A, const short* __restrict__ W,
         short* __restrict__ qh, short* __restrict__ kh_, _Float16* __restrict__ vp) {
  __shared__ short As[128 * 64];
  __shared__ short Bs[128 * 64];
  const int tid = threadIdx.x;
  const int lane = tid & 63;
  const int w = tid >> 6;
  const int ln16 = lane & 15;
  const int quad = lane >> 4;
  const int m_blk0 = blockIdx.x * 256;     // two 128-row tiles
  const int n_blk = blockIdx.y * 128;
  const int m0w = (w & 1) * 64;
  const int n0w = (w >> 1) * 64;
  const int srow = lane >> 3;
  const int swz = (lane & 7) ^ srow;

  int aoff[4];
  const short* bsrc[4];
  short* dst[8];
#pragma unroll
  for (int i = 0; i < 8; ++i) {
    const int grp = w + i * 4;
    if (i < 4) {
      aoff[i] = (grp * 8 + srow) * DIM + swz * 8;
      dst[i] = As + grp * 512;
    } else {
      const int gb = grp - 16;
      bsrc[i - 4] = W + (size_t)(n_blk + gb * 8 + srow) * DIM + swz * 8;
      dst[i] = Bs + gb * 512;
    }
  }

  auto stage = [&](int t2, int s2) {
    const short* At = A + (size_t)(m_blk0 + t2 * 128) * DIM + s2 * 64;
#pragma unroll
    for (int i = 0; i < 4; ++i) gl_lds16(At + aoff[i], dst[i]);
#pragma unroll
    for (int i = 0; i < 4; ++i) gl_lds16(bsrc[i] + s2 * 64, dst[i + 4]);
  };

  stage(0, 0);

#pragma unroll
  for (int t = 0; t < 2; ++t) {
    f32x4 acc[4][4] = {};
#pragma unroll
    for (int s = 0; s < 4; ++s) {
      __syncthreads();
      s16x8 af[2][4], bf[2][4];
#pragma unroll
      for (int kh = 0; kh < 2; ++kh) {
#pragma unroll
        for (int mt = 0; mt < 4; ++mt)
          af[kh][mt] = fragld(As, m0w + mt * 16 + ln16, kh * 4 + quad);
#pragma unroll
        for (int nt = 0; nt < 4; ++nt)
          bf[kh][nt] = fragld(Bs, n0w + nt * 16 + ln16, kh * 4 + quad);
      }
#pragma unroll
      for (int kh = 0; kh < 2; ++kh)
#pragma unroll
        for (int mt = 0; mt < 4; ++mt)
#pragma unroll
          for (int nt = 0; nt < 4; ++nt)
            acc[mt][nt] = __builtin_amdgcn_mfma_f32_16x16x32_bf16(af[kh][mt], bf[kh][nt], acc[mt][nt], 0, 0, 0);
      if (!(t == 1 && s == 3)) {
        __syncthreads();
        if (s == 3) stage(t + 1, 0);
        else        stage(t, s + 1);
      }
    }

#pragma unroll
    for (int mt = 0; mt < 4; ++mt) {
      const int m = m_blk0 + t * 128 + m0w + mt * 16 + quad * 4;
      const int bb = m >> 12;
      const int n = m & 4095;
#pragma unroll
      for (int nt = 0; nt < 4; ++nt) {
        const int f = n_blk + n0w + nt * 16;
        if (f < 512) {
          const int ff = f & 255;
          short* dstp = (f < 256 ? qh : kh_)
                       + ((size_t)(bb * 8 + (ff >> 5)) * SEQ + n) * 32 + (ff & 16) + ln16;
#pragma unroll
          for (int r = 0; r < 4; ++r) dstp[r * 32] = f2bf(acc[mt][nt][r]);
        } else {
          const int ff = f - 512;
          const int h = ff >> 5;
          const int d = (ff & 16) + ln16;
          const int within = n & 31;
          const int pos = (n & ~31) + ((within & 12) << 1) + ((within >> 4) << 2);
          f16x4 o;
#pragma unroll
          for (int r = 0; r < 4; ++r) o[r] = (_Float16)acc[mt][nt][r];
          *(f16x4*)(vp + ((size_t)(bb * 8 + h) * 32 + d) * SEQ + pos) = o;
        }
      }
    }
  }
}

// ---------------- Local attention: wave = half-window (4 q-tiles), prefetched ----------------
__global__ void __launch_bounds__(256)
attn_kernel(const short* __restrict__ qh, const short* __restrict__ kh,
            const _Float16* __restrict__ vp, short* __restrict__ out) {
  const int blk = blockIdx.x;              // 1024 blocks
  const int lane = threadIdx.x & 63;
  const int wid = threadIdx.x >> 6;
  const int ln16 = lane & 15;
  const int quad = lane >> 4;

  const int w = (blk & 15) * 2 + (wid >> 1);
  const int h = (blk >> 4) & 7;
  const int b = blk >> 7;
  const int plane = b * 8 + h;
  const int tok0 = w * 128 + (wid & 1) * 64;
  const int ktok = w * 128 - 128;
  const int c0 = (w == 0) ? 4 : 0;
  const int c1 = (w == NWIN - 1) ? 8 : 12;

  const short* qp = qh + ((size_t)plane * SEQ + tok0) * 32;
  s16x8 qf[4];
#pragma unroll
  for (int qi = 0; qi < 4; ++qi)
    qf[qi] = *(const s16x8*)(qp + (qi * 16 + ln16) * 32 + quad * 8);

  const short* kp = kh + ((size_t)plane * SEQ + ktok) * 32;
  const _Float16* vb = vp + ((size_t)plane * 32 + ln16) * SEQ + ktok;

  float lsum[4] = {0.f, 0.f, 0.f, 0.f};
  f32x4 ot[4][2] = {};

  s16x8 kc0 = *(const s16x8*)(kp + (c0 * 32 + ln16) * 32 + quad * 8);
  s16x8 kc1 = *(const s16x8*)(kp + (c0 * 32 + 16 + ln16) * 32 + quad * 8);
  f16x8 vc0 = *(const f16x8*)(vb + c0 * 32 + quad * 8);
  f16x8 vc1 = *(const f16x8*)(vb + (size_t)16 * SEQ + c0 * 32 + quad * 8);

  for (int c = c0; c < c1; ++c) {
    const int cn = (c + 1 < c1) ? c + 1 : c;
    s16x8 kn0 = *(const s16x8*)(kp + (cn * 32 + ln16) * 32 + quad * 8);
    s16x8 kn1 = *(const s16x8*)(kp + (cn * 32 + 16 + ln16) * 32 + quad * 8);
    f16x8 vn0 = *(const f16x8*)(vb + cn * 32 + quad * 8);
    f16x8 vn1 = *(const f16x8*)(vb + (size_t)16 * SEQ + cn * 32 + quad * 8);

    const f16x4 v00 = __builtin_shufflevector(vc0, vc0, 0, 1, 2, 3);
    const f16x4 v10 = __builtin_shufflevector(vc0, vc0, 4, 5, 6, 7);
    const f16x4 v01 = __builtin_shufflevector(vc1, vc1, 0, 1, 2, 3);
    const f16x4 v11 = __builtin_shufflevector(vc1, vc1, 4, 5, 6, 7);

#pragma unroll
    for (int qi = 0; qi < 4; ++qi) {
      const f32x4 z = {0.f, 0.f, 0.f, 0.f};
      f32x4 st0 = __builtin_amdgcn_mfma_f32_16x16x32_bf16(kc0, qf[qi], z, 0, 0, 0);
      f32x4 st1 = __builtin_amdgcn_mfma_f32_16x16x32_bf16(kc1, qf[qi], z, 0, 0, 0);
      float p[8];
#pragma unroll
      for (int r = 0; r < 4; ++r) {
        p[r]     = fast_exp2(st0[r] * ATT_SCALE_LOG2E);
        p[4 + r] = fast_exp2(st1[r] * ATT_SCALE_LOG2E);
      }
      lsum[qi] += ((p[0] + p[1]) + (p[2] + p[3])) + ((p[4] + p[5]) + (p[6] + p[7]));
      f16x4 pa, pb;
#pragma unroll
      for (int r = 0; r < 4; ++r) { pa[r] = (_Float16)p[r]; pb[r] = (_Float16)p[4 + r]; }
      ot[qi][0] = __builtin_amdgcn_mfma_f32_16x16x16f16(pa, v00, ot[qi][0], 0, 0, 0);
      ot[qi][1] = __builtin_amdgcn_mfma_f32_16x16x16f16(pa, v01, ot[qi][1], 0, 0, 0);
      ot[qi][0] = __builtin_amdgcn_mfma_f32_16x16x16f16(pb, v10, ot[qi][0], 0, 0, 0);
      ot[qi][1] = __builtin_amdgcn_mfma_f32_16x16x16f16(pb, v11, ot[qi][1], 0, 0, 0);
    }
    kc0 = kn0; kc1 = kn1; vc0 = vn0; vc1 = vn1;
  }

#pragma unroll
  for (int qi = 0; qi < 4; ++qi) {
    float l = lsum[qi];
    l += __shfl_xor(l, 16, 64);
    l += __shfl_xor(l, 32, 64);
    const float inv = 1.0f / l;
#pragma unroll
    for (int dt = 0; dt < 2; ++dt)
#pragma unroll
      for (int r = 0; r < 4; ++r)
        out[(size_t)(b * SEQ + tok0 + qi * 16 + quad * 4 + r) * DIM
            + h * DHEAD + dt * 16 + ln16] = f2bf(ot[qi][dt][r] * inv);
  }
}

// ---------------- merged weight conversion fp32 -> bf16 (with FF padding) ----------------
__global__ void cvt_all(const float* __restrict__ qkv_w, const float* __restrict__ out_w,
                        const float* __restrict__ ff_w1, const float* __restrict__ ff_w2,
                        short* __restrict__ wqkv, short* __restrict__ wout,
                        short* __restrict__ wff1, short* __restrict__ wff2) {
  int i = blockIdx.x * 256 + threadIdx.x;
  if (i < 786432) { wqkv[i] = f2bf(qkv_w[i]); return; }
  i -= 786432;
  if (i < 262144) { wout[i] = f2bf(out_w[i]); return; }
  i -= 262144;
  if (i < 1441792) {
    const int c = i & 255;
    const int rl = i >> 8;
    const int l = rl / 1408;
    const int r = rl - l * 1408;
    const int half = r / FFP;
    const int rr = r - half * FFP;
    const float v = (rr < 682) ? ff_w1[((size_t)(l * 1364 + half * 682 + rr)) * 256 + c] : 0.0f;
    wff1[i] = f2bf(v);
    return;
  }
  i -= 1441792;
  if (i < 720896) {
    const int c = i % FFP;
    const int t = i / FFP;
    const float v = (c < 682) ? ff_w2[(size_t)t * 682 + c] : 0.0f;
    wff2[i] = f2bf(v);
  }
}

// ---------------- driver ----------------
extern "C" void kernel_launch(void* const* d_in, const int* in_sizes, int n_in,
                              void* d_out, int out_size, void* d_ws, size_t ws_size,
                              hipStream_t stream) {
  const float* x0    = (const float*)d_in[0];
  const float* ln1_g = (const float*)d_in[2];
  const float* ln1_b = (const float*)d_in[3];
  const float* qkv_w = (const float*)d_in[4];
  const float* out_w = (const float*)d_in[5];
  const float* ln2_g = (const float*)d_in[6];
  const float* ln2_b = (const float*)d_in[7];
  const float* ff_w1 = (const float*)d_in[8];
  const float* ff_w2 = (const float*)d_in[9];
  float* x = (float*)d_out;

  char* ws = (char*)d_ws;
  short* wqkv = (short*)(ws);                    //  4*768*256 bf16
  short* wout = (short*)(ws + 1572864);          //  4*256*256
  short* wff1 = (short*)(ws + 2097152);          //  4*1408*256
  short* wff2 = (short*)(ws + 4980736);          //  4*256*704
  short* xn   = (short*)(ws + 6422528);          //  32768*256 (LN out / attn out)
  short*    qhb = (short*)(ws + 23199744);                 // 16.8MB qkv->attn
  short*    khb = (short*)(ws + 23199744 + 16777216);      // 16.8MB qkv->attn
  _Float16* vpb = (_Float16*)(ws + 23199744 + 33554432);   // 16.8MB qkv->attn
  short*    yb  = (short*)(ws + 23199744);                 // 46.1MB fused->ff2 (disjoint lifetime)

  copy_ln<<<8192, 256, 0, stream>>>(x0, ln1_g, ln1_b, x, xn);
  cvt_all<<<12544, 256, 0, stream>>>(qkv_w, out_w, ff_w1, ff_w2, wqkv, wout, wff1, wff2);

  for (int l = 0; l < 4; ++l) {
    gemm_qkv<<<dim3(128, 6), 256, 0, stream>>>(
        xn, wqkv + (size_t)l * 768 * DIM, qhb, khb, vpb);
    attn_kernel<<<1024, 256, 0, stream>>>(qhb, khb, vpb, xn);
    fused_out_ff1<<<512, 256, 0, stream>>>(
        xn, wout + (size_t)l * DIM * DIM, x,
        ln2_g + l * DIM, ln2_b + l * DIM,
        wff1 + (size_t)l * 2 * FFP * DIM, yb);
    if (l < 3)
      gemm_res_ln<FFP, true><<<512, 256, 0, stream>>>(
          yb, wff2 + (size_t)l * DIM * FFP, x,
          ln1_g + (l + 1) * DIM, ln1_b + (l + 1) * DIM, xn);
    else
      gemm_res_ln<FFP, false><<<512, 256, 0, stream>>>(
          yb, wff2 + (size_t)l * DIM * FFP, x, nullptr, nullptr, nullptr);
  }
}